// Round 10
// baseline (155.439 us; speedup 1.0000x reference)
//
#include <hip/hip_runtime.h>
#include <hip/hip_bf16.h>
#include <stdint.h>

#define NROWS 2048
#define DIM   4096
#define NACT  684
#define INV_TEMP 10.0f
#define NT256 36         // 8*9/2 upper-triangle 256x256 tiles
#define KSPLIT 8
#define KSEG  512        // DIM / KSPLIT
#define KITER 16         // KSEG / 32
#define FP8_SCALE 16.0f  // Y stored as fp8(y*16); dot = 256*cos
#define PART_SCALE (1.0f / 256.0f)

// s_waitcnt immediates (gfx9/CDNA: vmcnt[3:0]@0, expcnt@4, lgkmcnt@8, vmcnt[5:4]@14)
#define WAITCNT_VM0   0x0F70
#define WAITCNT_VM2   0x0F72
#define WAITCNT_VM4   0x0F74

typedef __attribute__((ext_vector_type(4))) float floatx4;
typedef __attribute__((ext_vector_type(8))) short shortx8;
typedef __attribute__((ext_vector_type(8))) unsigned short ushortx8;

static __device__ __forceinline__ unsigned short f32_to_bf16(float f) {
  union { float f; unsigned int u; } v; v.f = f;
  unsigned int u = v.u;
  unsigned int r = u + 0x7fffu + ((u >> 16) & 1u);
  return (unsigned short)(r >> 16);
}
static __device__ __forceinline__ float bf16_to_f32(unsigned short u) {
  union { unsigned int u; float f; } v; v.u = ((unsigned int)u) << 16;
  return v.f;
}
static __device__ __forceinline__ unsigned short f32_to_f16(float f) {
  _Float16 h = (_Float16)f;
  union { _Float16 h; unsigned short u; } v; v.h = h;
  return v.u;
}
static __device__ __forceinline__ float f16_to_f32(unsigned short u) {
  union { unsigned short u; _Float16 h; } v; v.u = u;
  return (float)v.h;
}

// ------- Kernel 1A: per-row L2 norm + fp8 e4m3 convert (y*16) -------
__global__ __launch_bounds__(256) void k_normconv_fp8(const float* __restrict__ X,
                                                      unsigned char* __restrict__ Yq) {
  const int row = blockIdx.x;
  const float4* xr = (const float4*)(X + (size_t)row * DIM);
  float4 v[4];
  float s = 0.f;
#pragma unroll
  for (int t = 0; t < 4; t++) {
    float4 w = xr[threadIdx.x * 4 + t];
    v[t] = w;
    s += w.x * w.x + w.y * w.y + w.z * w.z + w.w * w.w;
  }
#pragma unroll
  for (int off = 32; off > 0; off >>= 1) s += __shfl_down(s, off, 64);
  __shared__ float wsum[4];
  if ((threadIdx.x & 63) == 0) wsum[threadIdx.x >> 6] = s;
  __syncthreads();
  const float total = wsum[0] + wsum[1] + wsum[2] + wsum[3];
  const float sc = FP8_SCALE / fmaxf(sqrtf(total), 1e-30f);
  uint4 o;
  unsigned int r0;
  r0 = __builtin_amdgcn_cvt_pk_fp8_f32(v[0].x * sc, v[0].y * sc, 0, false);
  o.x = __builtin_amdgcn_cvt_pk_fp8_f32(v[0].z * sc, v[0].w * sc, r0, true);
  r0 = __builtin_amdgcn_cvt_pk_fp8_f32(v[1].x * sc, v[1].y * sc, 0, false);
  o.y = __builtin_amdgcn_cvt_pk_fp8_f32(v[1].z * sc, v[1].w * sc, r0, true);
  r0 = __builtin_amdgcn_cvt_pk_fp8_f32(v[2].x * sc, v[2].y * sc, 0, false);
  o.z = __builtin_amdgcn_cvt_pk_fp8_f32(v[2].z * sc, v[2].w * sc, r0, true);
  r0 = __builtin_amdgcn_cvt_pk_fp8_f32(v[3].x * sc, v[3].y * sc, 0, false);
  o.w = __builtin_amdgcn_cvt_pk_fp8_f32(v[3].z * sc, v[3].w * sc, r0, true);
  ((uint4*)(Yq + (size_t)row * DIM))[threadIdx.x] = o;
}

// ------- Kernel 2A: symmetric split-K GEMM, fp8, 256x256 tile, 512 thr, 3-stage -------
// grid NT256*KSPLIT. Wave (4x2): wr=wave>>1 rows wr*64, wc=wave&1 cols wc*128.
// Per wave per BK=32 iter: 4x8 = 32 MFMA. acc = 128 VGPR/lane.
__global__ __launch_bounds__(512, 2) void k_gemm_sym(const unsigned char* __restrict__ Yq,
                                                     unsigned short* __restrict__ P) {
  __shared__ __attribute__((aligned(16))) unsigned char lds[3 * 16384];
  const int bid = blockIdx.x;
  const int kz = bid & 7;
  const int t  = bid >> 3;
  int ti = 0, rem = t;
  while (rem >= 8 - ti) { rem -= 8 - ti; ti++; }
  const int tj = ti + rem;
  const int row0 = ti * 256;
  const int col0 = tj * 256;
  const int kbase = kz * KSEG;

  const int tid  = threadIdx.x;
  const int lane = tid & 63;
  const int wave = tid >> 6;      // 0..7
  const int wr = wave >> 1;       // 0..3 -> rows wr*64
  const int wc = wave & 1;        // 0..1 -> cols wc*128

  floatx4 zero = {0.f, 0.f, 0.f, 0.f};
  floatx4 acc[4][8];
#pragma unroll
  for (int i = 0; i < 4; i++)
#pragma unroll
    for (int j = 0; j < 8; j++) acc[i][j] = zero;

  // staging: thread t covers LDS bytes [16t,16t+16): row = t>>1 (0..255), colbyte (t&1)*16
  const unsigned char* gA = Yq + (size_t)(row0 + (tid >> 1)) * DIM + kbase + (tid & 1) * 16;
  const unsigned char* gB = Yq + (size_t)(col0 + (tid >> 1)) * DIM + kbase + (tid & 1) * 16;

  const int fr  = lane & 15;
  const int fc8 = (lane >> 4) * 8;

#define ISSUE(st, koff)                                                                 \
  do {                                                                                  \
    __builtin_amdgcn_global_load_lds(                                                   \
        (const __attribute__((address_space(1))) void*)(gA + (koff)),                   \
        (__attribute__((address_space(3))) void*)(lds + (st) * 16384 + tid * 16),       \
        16, 0, 0);                                                                      \
    __builtin_amdgcn_global_load_lds(                                                   \
        (const __attribute__((address_space(1))) void*)(gB + (koff)),                   \
        (__attribute__((address_space(3))) void*)(lds + (st) * 16384 + 8192 + tid * 16),\
        16, 0, 0);                                                                      \
  } while (0)

#define COMPUTE(st)                                                                     \
  do {                                                                                  \
    const unsigned char* bA = lds + (st) * 16384;                                       \
    const unsigned char* bB = bA + 8192;                                                \
    long long af[4], bf[8];                                                             \
    _Pragma("unroll")                                                                   \
    for (int mi = 0; mi < 4; mi++)                                                      \
      af[mi] = *(const long long*)(bA + (wr * 64 + mi * 16 + fr) * 32 + fc8);           \
    _Pragma("unroll")                                                                   \
    for (int ni = 0; ni < 8; ni++)                                                      \
      bf[ni] = *(const long long*)(bB + (wc * 128 + ni * 16 + fr) * 32 + fc8);          \
    _Pragma("unroll")                                                                   \
    for (int mi = 0; mi < 4; mi++)                                                      \
      _Pragma("unroll")                                                                 \
      for (int ni = 0; ni < 8; ni++)                                                    \
        acc[mi][ni] = __builtin_amdgcn_mfma_f32_16x16x32_fp8_fp8(af[mi], bf[ni],        \
                                                                 acc[mi][ni], 0, 0, 0); \
  } while (0)

  ISSUE(0, 0);
  ISSUE(1, 32);
#pragma unroll
  for (int k = 0; k < KITER; k++) {
    const int cur = k % 3;
    if (k < KITER - 2) {
      ISSUE((k + 2) % 3, (k + 2) * 32);
      __builtin_amdgcn_s_waitcnt(WAITCNT_VM4);   // cur's 2 loads landed; 4 in flight
    } else if (k == KITER - 2) {
      __builtin_amdgcn_s_waitcnt(WAITCNT_VM2);
    } else {
      __builtin_amdgcn_s_waitcnt(WAITCNT_VM0);
    }
    __builtin_amdgcn_sched_barrier(0);
    __builtin_amdgcn_s_barrier();
    COMPUTE(cur);
    if (k < KITER - 1) {
      __builtin_amdgcn_s_barrier();
      __builtin_amdgcn_sched_barrier(0);
    }
  }

#undef ISSUE
#undef COMPUTE

  // Epilogue: partial = acc/256 (bf16), COL-MAJOR per 256-tile (col*256 + row).
  unsigned short* dst = P + (size_t)(t * KSPLIT + kz) * 65536;
  const int cc  = lane & 15;
  const int cr4 = (lane >> 4) * 4;
#pragma unroll
  for (int mi = 0; mi < 4; mi++) {
    const int row = wr * 64 + mi * 16 + cr4;
#pragma unroll
    for (int ni = 0; ni < 8; ni++) {
      const int col = wc * 128 + ni * 16 + cc;
      unsigned int d0 = (unsigned int)f32_to_bf16(acc[mi][ni][0] * PART_SCALE) |
                        ((unsigned int)f32_to_bf16(acc[mi][ni][1] * PART_SCALE) << 16);
      unsigned int d1 = (unsigned int)f32_to_bf16(acc[mi][ni][2] * PART_SCALE) |
                        ((unsigned int)f32_to_bf16(acc[mi][ni][3] * PART_SCALE) << 16);
      uint2 v; v.x = d0; v.y = d1;
      *(uint2*)(dst + (size_t)col * 256 + row) = v;
    }
  }
}

// ---- Kernel 3A: combine partials (col-major 256-tile) -> S fp16 both triangles + T ----
// grid (NT256, 16): block covers 16 tile-cols x 256 rows. cl=tid>>4, q=tid&15.
__global__ __launch_bounds__(256) void k_combine(const unsigned short* __restrict__ P,
                                                 unsigned short* __restrict__ S,
                                                 float* __restrict__ T) {
  __shared__ float tileS[16][258];
  __shared__ float tileE[16][258];
  const int t = blockIdx.x;
  const int h = blockIdx.y;          // col 16-group
  int ti = 0, rem = t;
  while (rem >= 8 - ti) { rem -= 8 - ti; ti++; }
  const int tj = ti + rem;
  const int gr = ti * 256, gc = tj * 256;
  const int c0 = h * 16;
  const int tid = threadIdx.x;
  const int cl = tid >> 4;           // local col 0..15
  const int q  = tid & 15;           // row chunk (16 rows)

  float acc[16];
#pragma unroll
  for (int j = 0; j < 16; j++) acc[j] = 0.f;
#pragma unroll
  for (int kz = 0; kz < KSPLIT; kz++) {
    const ushortx8* p = (const ushortx8*)(P + (size_t)(t * KSPLIT + kz) * 65536 +
                                          (size_t)(c0 + cl) * 256 + q * 16);
#pragma unroll
    for (int c = 0; c < 2; c++) {
      ushortx8 u = p[c];
#pragma unroll
      for (int e = 0; e < 8; e++) acc[c * 8 + e] += bf16_to_f32((unsigned short)u[e]);
    }
  }
  float cs = 0.f;
  unsigned short hv[16];
#pragma unroll
  for (int j = 0; j < 16; j++) {
    float v = acc[j] * INV_TEMP;
    float ev = __expf(v);
    hv[j] = f32_to_f16(v);
    tileS[cl][q * 16 + j] = v;
    tileE[cl][q * 16 + j] = ev;
    cs += ev;
  }
  // mirror write: S[gc+col][gr + q*16 .. +16]. Covers diagonal tiles fully.
  {
    uint4* srow = (uint4*)(S + (size_t)(gc + c0 + cl) * NROWS + gr + q * 16);
#pragma unroll
    for (int u = 0; u < 2; u++) {
      uint4 w;
      w.x = (unsigned int)hv[u * 8 + 0] | ((unsigned int)hv[u * 8 + 1] << 16);
      w.y = (unsigned int)hv[u * 8 + 2] | ((unsigned int)hv[u * 8 + 3] << 16);
      w.z = (unsigned int)hv[u * 8 + 4] | ((unsigned int)hv[u * 8 + 5] << 16);
      w.w = (unsigned int)hv[u * 8 + 6] | ((unsigned int)hv[u * 8 + 7] << 16);
      srow[u] = w;
    }
  }
  // column sum -> T[gc+col]; reduce over the 16 q-lanes
  cs += __shfl_xor(cs, 1, 64);
  cs += __shfl_xor(cs, 2, 64);
  cs += __shfl_xor(cs, 4, 64);
  cs += __shfl_xor(cs, 8, 64);
  if (q == 0) atomicAdd(&T[gc + c0 + cl], cs);

  if (ti != tj) {
    __syncthreads();
    // direct phase: one thread per row r=tid (0..255), 16 cols
    const int r = tid;
    float rs = 0.f;
    unsigned short hv2[16];
#pragma unroll
    for (int c = 0; c < 16; c++) {
      hv2[c] = f32_to_f16(tileS[c][r]);
      rs += tileE[c][r];
    }
    uint4* drow = (uint4*)(S + (size_t)(gr + r) * NROWS + gc + c0);
#pragma unroll
    for (int u = 0; u < 2; u++) {
      uint4 w;
      w.x = (unsigned int)hv2[u * 8 + 0] | ((unsigned int)hv2[u * 8 + 1] << 16);
      w.y = (unsigned int)hv2[u * 8 + 2] | ((unsigned int)hv2[u * 8 + 3] << 16);
      w.z = (unsigned int)hv2[u * 8 + 4] | ((unsigned int)hv2[u * 8 + 5] << 16);
      w.w = (unsigned int)hv2[u * 8 + 6] | ((unsigned int)hv2[u * 8 + 7] << 16);
      drow[u] = w;
    }
    atomicAdd(&T[gr + r], rs);
  }
}

// ---- Kernel 4A: merged Dsum + pair losses. One wave per active row p. ----
__global__ __launch_bounds__(64) void k_tail(const unsigned short* __restrict__ S,
                                             const float* __restrict__ T,
                                             float* __restrict__ out) {
  const int p = blockIdx.x;
  const int a = 12 * (p >> 2) + (p & 3);
  const int lane = threadIdx.x;
  const int m = a >> 2;
  const int c = a & 3;
  __shared__ float Dsh[6];
#pragma unroll
  for (int k = 0; k < 6; k++) {
    const int row = (a + 4 * k) & (NROWS - 1);
    const uint2* sr = (const uint2*)(S + (size_t)row * NROWS);
    float s = 0.f;
    uint2 v0 = sr[(m + lane) & 511];
    uint2 v1 = sr[(m + 64 + lane) & 511];
    unsigned short e0 = (c < 2) ? (unsigned short)(v0.x >> (16 * c))
                                : (unsigned short)(v0.y >> (16 * (c - 2)));
    unsigned short e1 = (c < 2) ? (unsigned short)(v1.x >> (16 * c))
                                : (unsigned short)(v1.y >> (16 * (c - 2)));
    s += __expf(f16_to_f32(e0)) + __expf(f16_to_f32(e1));
    if (lane < 32) {
      uint2 v2 = sr[(m + 128 + lane) & 511];
      unsigned short e2 = (c < 2) ? (unsigned short)(v2.x >> (16 * c))
                                  : (unsigned short)(v2.y >> (16 * (c - 2)));
      s += __expf(f16_to_f32(e2));
    }
#pragma unroll
    for (int off = 32; off > 0; off >>= 1) s += __shfl_down(s, off, 64);
    if (lane == 0) Dsh[k] = T[row] - s;
  }
  __syncthreads();
  const int pa[7] = {0, 1, 0, 3, 4, 1, 2};
  const int pb[7] = {1, 2, 3, 4, 5, 4, 5};
  float s2 = 0.f;
  if (lane < 7) {
    const int ra = (a + 4 * pa[lane]) & (NROWS - 1);
    const int rb = (a + 4 * pb[lane]) & (NROWS - 1);
    const float num = f16_to_f32(S[(size_t)ra * NROWS + rb]);
    const float en = __expf(num);
    s2 = __logf(en + Dsh[pa[lane]]) + __logf(en + Dsh[pb[lane]]) - 2.f * num;
  }
#pragma unroll
  for (int off = 32; off > 0; off >>= 1) s2 += __shfl_down(s2, off, 64);
  if (lane == 0) atomicAdd(out, s2 * (1.0f / (6.0f * 512.0f)));
}

// ------------- Path B kernels (fallback when ws is small; fp32 S) -------------
__global__ __launch_bounds__(256) void k_normconv(const float* __restrict__ X,
                                                  unsigned short* __restrict__ Y) {
  const int row = blockIdx.x;
  const float4* xr = (const float4*)(X + (size_t)row * DIM);
  float4 v[4];
  float s = 0.f;
#pragma unroll
  for (int t = 0; t < 4; t++) {
    float4 w = xr[threadIdx.x + t * 256];
    v[t] = w;
    s += w.x * w.x + w.y * w.y + w.z * w.z + w.w * w.w;
  }
#pragma unroll
  for (int off = 32; off > 0; off >>= 1) s += __shfl_down(s, off, 64);
  __shared__ float wsum[4];
  if ((threadIdx.x & 63) == 0) wsum[threadIdx.x >> 6] = s;
  __syncthreads();
  const float total = wsum[0] + wsum[1] + wsum[2] + wsum[3];
  const float inv = 1.0f / fmaxf(sqrtf(total), 1e-30f);
  ushort4* yr = (ushort4*)(Y + (size_t)row * DIM);
#pragma unroll
  for (int t = 0; t < 4; t++) {
    float4 w = v[t];
    ushort4 o;
    o.x = f32_to_bf16(w.x * inv);
    o.y = f32_to_bf16(w.y * inv);
    o.z = f32_to_bf16(w.z * inv);
    o.w = f32_to_bf16(w.w * inv);
    yr[threadIdx.x + t * 256] = o;
  }
}

__global__ __launch_bounds__(256) void k_gemm(const unsigned short* __restrict__ Y,
                                              float* __restrict__ S) {
  __shared__ __attribute__((aligned(16))) unsigned short sA[128 * 32];
  __shared__ __attribute__((aligned(16))) unsigned short sB[128 * 32];
  const int tid  = threadIdx.x;
  const int lane = tid & 63;
  const int wave = tid >> 6;
  const int wr = wave >> 1;
  const int wc = wave & 1;
  const int row0 = blockIdx.y * 128;
  const int col0 = blockIdx.x * 128;

  floatx4 zero = {0.f, 0.f, 0.f, 0.f};
  floatx4 acc[4][4];
#pragma unroll
  for (int i = 0; i < 4; i++)
#pragma unroll
    for (int j = 0; j < 4; j++) acc[i][j] = zero;

  const int sr = tid >> 2;
  const int sc = (tid & 3) * 8;
  const unsigned short* gA0 = Y + (size_t)(row0 + sr) * DIM + sc;
  const unsigned short* gA1 = gA0 + (size_t)64 * DIM;
  const unsigned short* gB0 = Y + (size_t)(col0 + sr) * DIM + sc;
  const unsigned short* gB1 = gB0 + (size_t)64 * DIM;

  const int fr = lane & 15;
  const int fc = (lane >> 4) * 8;

  for (int k0 = 0; k0 < DIM; k0 += 32) {
    __builtin_amdgcn_global_load_lds(
        (const __attribute__((address_space(1))) void*)(gA0 + k0),
        (__attribute__((address_space(3))) void*)(sA + tid * 8), 16, 0, 0);
    __builtin_amdgcn_global_load_lds(
        (const __attribute__((address_space(1))) void*)(gA1 + k0),
        (__attribute__((address_space(3))) void*)(sA + 2048 + tid * 8), 16, 0, 0);
    __builtin_amdgcn_global_load_lds(
        (const __attribute__((address_space(1))) void*)(gB0 + k0),
        (__attribute__((address_space(3))) void*)(sB + tid * 8), 16, 0, 0);
    __builtin_amdgcn_global_load_lds(
        (const __attribute__((address_space(1))) void*)(gB1 + k0),
        (__attribute__((address_space(3))) void*)(sB + 2048 + tid * 8), 16, 0, 0);
    __syncthreads();

    shortx8 af[4], bf[4];
#pragma unroll
    for (int mi = 0; mi < 4; mi++)
      af[mi] = *(const shortx8*)(sA + (wr * 64 + mi * 16 + fr) * 32 + fc);
#pragma unroll
    for (int ni = 0; ni < 4; ni++)
      bf[ni] = *(const shortx8*)(sB + (wc * 64 + ni * 16 + fr) * 32 + fc);
#pragma unroll
    for (int mi = 0; mi < 4; mi++)
#pragma unroll
      for (int ni = 0; ni < 4; ni++)
        acc[mi][ni] = __builtin_amdgcn_mfma_f32_16x16x32_bf16(af[mi], bf[ni], acc[mi][ni], 0, 0, 0);
    __syncthreads();
  }

  const int cc  = lane & 15;
  const int cr4 = (lane >> 4) * 4;
#pragma unroll
  for (int mi = 0; mi < 4; mi++) {
    const int row = row0 + wr * 64 + mi * 16 + cr4;
#pragma unroll
    for (int ni = 0; ni < 4; ni++) {
      const int col = col0 + wc * 64 + ni * 16 + cc;
      float* dst = S + (size_t)row * NROWS + col;
#pragma unroll
      for (int r = 0; r < 4; r++) dst[(size_t)r * NROWS] = acc[mi][ni][r] * INV_TEMP;
    }
  }
}

__global__ __launch_bounds__(256) void k_rowsum(const float* __restrict__ S,
                                                float* __restrict__ T) {
  const int row = blockIdx.x;
  const float* sr = S + (size_t)row * NROWS;
  float s = 0.f;
  for (int b = threadIdx.x; b < NROWS; b += 256) s += __expf(sr[b]);
#pragma unroll
  for (int off = 32; off > 0; off >>= 1) s += __shfl_down(s, off, 64);
  __shared__ float wsum[4];
  if ((threadIdx.x & 63) == 0) wsum[threadIdx.x >> 6] = s;
  __syncthreads();
  if (threadIdx.x == 0) T[row] = wsum[0] + wsum[1] + wsum[2] + wsum[3];
}

__global__ __launch_bounds__(64) void k_dsum(const float* __restrict__ S,
                                             const float* __restrict__ T,
                                             float* __restrict__ Ds) {
  const int p = blockIdx.x;
  const int k = blockIdx.y;
  const int a = 12 * (p >> 2) + (p & 3);
  const int lane = threadIdx.x;
  const int row = (a + 4 * k) & (NROWS - 1);
  const int m = a >> 2;
  const int c = a & 3;
  const float4* sr4 = (const float4*)(S + (size_t)row * NROWS);
  float s = 0.f;
  {
    float4 v0 = sr4[(m + lane) & 511];
    float4 v1 = sr4[(m + 64 + lane) & 511];
    float e0 = c == 0 ? v0.x : c == 1 ? v0.y : c == 2 ? v0.z : v0.w;
    float e1 = c == 0 ? v1.x : c == 1 ? v1.y : c == 2 ? v1.z : v1.w;
    s += __expf(e0) + __expf(e1);
    if (lane < 32) {
      float4 v2 = sr4[(m + 128 + lane) & 511];
      float e2 = c == 0 ? v2.x : c == 1 ? v2.y : c == 2 ? v2.z : v2.w;
      s += __expf(e2);
    }
  }
#pragma unroll
  for (int off = 32; off > 0; off >>= 1) s += __shfl_down(s, off, 64);
  if (lane == 0) Ds[p * 6 + k] = T[row] - s;
}

__global__ __launch_bounds__(256) void k_final(const float* __restrict__ S,
                                               const float* __restrict__ Ds,
                                               float* __restrict__ out) {
  const int pa[7] = {0, 1, 0, 3, 4, 1, 2};
  const int pb[7] = {1, 2, 3, 4, 5, 4, 5};
  const int idx = blockIdx.x * 256 + threadIdx.x;
  float s = 0.f;
  if (idx < NACT * 7) {
    const int p = idx / 7;
    const int q = idx - p * 7;
    const int a0 = 12 * (p >> 2) + (p & 3);
    const int ra = (a0 + 4 * pa[q]) & (NROWS - 1);
    const int rb = (a0 + 4 * pb[q]) & (NROWS - 1);
    const float num = S[(size_t)ra * NROWS + rb];
    const float en = __expf(num);
    s = __logf(en + Ds[p * 6 + pa[q]]) + __logf(en + Ds[p * 6 + pb[q]]) - 2.f * num;
  }
#pragma unroll
  for (int off = 32; off > 0; off >>= 1) s += __shfl_down(s, off, 64);
  if ((threadIdx.x & 63) == 0) atomicAdd(out, s * (1.0f / (6.0f * 512.0f)));
}

extern "C" void kernel_launch(void* const* d_in, const int* in_sizes, int n_in,
                              void* d_out, int out_size, void* d_ws, size_t ws_size,
                              hipStream_t stream) {
  const float* X = (const float*)d_in[0];
  char* ws = (char*)d_ws;
  float* out = (float*)d_out;

  // Path A layout: Yq [0,8M) | P [8M, 8M+36.9M) | S16 [46M, 54M) | T [54M, +8K)
  const size_t pOffA  = (size_t)8 * 1024 * 1024;
  const size_t pBytesA = (size_t)NT256 * KSPLIT * 65536 * 2;    // 37.75 MB
  const size_t sOffA  = (size_t)46 * 1024 * 1024;
  const size_t tOffA  = (size_t)54 * 1024 * 1024;
  const size_t needA  = tOffA + NROWS * 4 + 256;

  hipMemsetAsync(out, 0, sizeof(float), stream);

  if (ws_size >= needA) {
    unsigned char* Yq = (unsigned char*)ws;
    unsigned short* P = (unsigned short*)(ws + pOffA);
    unsigned short* S16 = (unsigned short*)(ws + sOffA);
    float* T = (float*)(ws + tOffA);
    hipMemsetAsync(T, 0, NROWS * sizeof(float), stream);
    hipLaunchKernelGGL(k_normconv_fp8, dim3(NROWS), dim3(256), 0, stream, X, Yq);
    hipLaunchKernelGGL(k_gemm_sym, dim3(NT256 * KSPLIT), dim3(512), 0, stream, Yq, P);
    hipLaunchKernelGGL(k_combine, dim3(NT256, 16), dim3(256), 0, stream, P, S16, T);
    hipLaunchKernelGGL(k_tail, dim3(NACT), dim3(64), 0, stream, S16, T, out);
  } else {
    unsigned short* Y = (unsigned short*)ws;                      // 16 MB bf16
    float* S = (float*)(ws + (size_t)16 * 1024 * 1024);           // 16 MB fp32
    float* T  = (float*)(ws + (size_t)32 * 1024 * 1024);
    float* Ds = (float*)(ws + (size_t)32 * 1024 * 1024 + 8192);
    hipLaunchKernelGGL(k_normconv, dim3(NROWS), dim3(256), 0, stream, X, Y);
    hipLaunchKernelGGL(k_gemm, dim3(16, 16), dim3(256), 0, stream, Y, S);
    hipLaunchKernelGGL(k_rowsum, dim3(NROWS), dim3(256), 0, stream, S, T);
    hipLaunchKernelGGL(k_dsum, dim3(NACT, 6), dim3(64), 0, stream, S, T, Ds);
    hipLaunchKernelGGL(k_final, dim3((NACT * 7 + 255) / 256), dim3(256), 0, stream, S, Ds, out);
  }
}

// Round 11
// 128.557 us; speedup vs baseline: 1.2091x; 1.2091x over previous
//
#include <hip/hip_runtime.h>
#include <hip/hip_bf16.h>
#include <stdint.h>

#define NROWS 2048
#define DIM   4096
#define NACT  684
#define INV_TEMP 10.0f
#define NTILE 136        // 16*17/2 upper-triangle 128x128 tiles
#define KSPLIT 4
#define KSEG  1024       // DIM / KSPLIT
#define KITER 16         // KSEG / 64  (BK=64 per stage)
#define FP8_SCALE 16.0f  // Y stored as fp8(y*16); dot = 256*cos
#define PART_SCALE (1.0f / 256.0f)

// s_waitcnt immediates (gfx9/CDNA: vmcnt[3:0]@0, expcnt@4, lgkmcnt@8, vmcnt[5:4]@14)
#define WAITCNT_VM0   0x0F70
#define WAITCNT_VM4   0x0F74
#define WAITCNT_VM8   0x0F78

typedef __attribute__((ext_vector_type(4))) float floatx4;
typedef __attribute__((ext_vector_type(8))) short shortx8;
typedef __attribute__((ext_vector_type(8))) unsigned short ushortx8;

static __device__ __forceinline__ unsigned short f32_to_bf16(float f) {
  union { float f; unsigned int u; } v; v.f = f;
  unsigned int u = v.u;
  unsigned int r = u + 0x7fffu + ((u >> 16) & 1u);
  return (unsigned short)(r >> 16);
}
static __device__ __forceinline__ float bf16_to_f32(unsigned short u) {
  union { unsigned int u; float f; } v; v.u = ((unsigned int)u) << 16;
  return v.f;
}
static __device__ __forceinline__ unsigned short f32_to_f16(float f) {
  _Float16 h = (_Float16)f;
  union { _Float16 h; unsigned short u; } v; v.h = h;
  return v.u;
}
static __device__ __forceinline__ float f16_to_f32(unsigned short u) {
  union { unsigned short u; _Float16 h; } v; v.u = u;
  return (float)v.h;
}

// ------- Kernel 1A: per-row L2 norm + fp8 e4m3 convert (y*16) -------
__global__ __launch_bounds__(256) void k_normconv_fp8(const float* __restrict__ X,
                                                      unsigned char* __restrict__ Yq) {
  const int row = blockIdx.x;
  const float4* xr = (const float4*)(X + (size_t)row * DIM);
  float4 v[4];
  float s = 0.f;
#pragma unroll
  for (int t = 0; t < 4; t++) {
    float4 w = xr[threadIdx.x * 4 + t];
    v[t] = w;
    s += w.x * w.x + w.y * w.y + w.z * w.z + w.w * w.w;
  }
#pragma unroll
  for (int off = 32; off > 0; off >>= 1) s += __shfl_down(s, off, 64);
  __shared__ float wsum[4];
  if ((threadIdx.x & 63) == 0) wsum[threadIdx.x >> 6] = s;
  __syncthreads();
  const float total = wsum[0] + wsum[1] + wsum[2] + wsum[3];
  const float sc = FP8_SCALE / fmaxf(sqrtf(total), 1e-30f);
  uint4 o;
  unsigned int r0;
  r0 = __builtin_amdgcn_cvt_pk_fp8_f32(v[0].x * sc, v[0].y * sc, 0, false);
  o.x = __builtin_amdgcn_cvt_pk_fp8_f32(v[0].z * sc, v[0].w * sc, r0, true);
  r0 = __builtin_amdgcn_cvt_pk_fp8_f32(v[1].x * sc, v[1].y * sc, 0, false);
  o.y = __builtin_amdgcn_cvt_pk_fp8_f32(v[1].z * sc, v[1].w * sc, r0, true);
  r0 = __builtin_amdgcn_cvt_pk_fp8_f32(v[2].x * sc, v[2].y * sc, 0, false);
  o.z = __builtin_amdgcn_cvt_pk_fp8_f32(v[2].z * sc, v[2].w * sc, r0, true);
  r0 = __builtin_amdgcn_cvt_pk_fp8_f32(v[3].x * sc, v[3].y * sc, 0, false);
  o.w = __builtin_amdgcn_cvt_pk_fp8_f32(v[3].z * sc, v[3].w * sc, r0, true);
  ((uint4*)(Yq + (size_t)row * DIM))[threadIdx.x] = o;
}

// ------- Kernel 2A: symmetric split-K(4) GEMM, fp8, BK=64 stages, 3-stage pipeline -------
// Stage = 16 KB: A-plane0(4K) A-plane1(4K) B-plane0(4K) B-plane1(4K), each plane 128x32 fp8
// in the proven conflict-layout. 32 MFMA per barrier-pair (2x R9).
__global__ __launch_bounds__(256) void k_gemm_sym(const unsigned char* __restrict__ Yq,
                                                  unsigned short* __restrict__ P) {
  __shared__ __attribute__((aligned(16))) unsigned char lds[3 * 16384];
  const int bid = blockIdx.x;
  const int kz = bid & 3;
  const int t  = bid >> 2;
  int ti = 0, rem = t;
  while (rem >= 16 - ti) { rem -= 16 - ti; ti++; }
  const int tj = ti + rem;
  const int row0 = ti * 128;
  const int col0 = tj * 128;
  const int kbase = kz * KSEG;

  const int tid  = threadIdx.x;
  const int lane = tid & 63;
  const int wave = tid >> 6;
  const int wr = wave >> 1;
  const int wc = wave & 1;

  floatx4 zero = {0.f, 0.f, 0.f, 0.f};
  floatx4 acc[4][4];
#pragma unroll
  for (int i = 0; i < 4; i++)
#pragma unroll
    for (int j = 0; j < 4; j++) acc[i][j] = zero;

  // per-plane staging: thread t covers row (t>>1), colbytes (t&1)*16 of a 128x32 plane
  const unsigned char* gA = Yq + (size_t)(row0 + (tid >> 1)) * DIM + kbase + (tid & 1) * 16;
  const unsigned char* gB = Yq + (size_t)(col0 + (tid >> 1)) * DIM + kbase + (tid & 1) * 16;

  const int fr  = lane & 15;
  const int fc8 = (lane >> 4) * 8;

#define ISSUE(st, koff)                                                                  \
  do {                                                                                   \
    unsigned char* base = lds + (st) * 16384;                                            \
    __builtin_amdgcn_global_load_lds(                                                    \
        (const __attribute__((address_space(1))) void*)(gA + (koff)),                    \
        (__attribute__((address_space(3))) void*)(base + tid * 16), 16, 0, 0);           \
    __builtin_amdgcn_global_load_lds(                                                    \
        (const __attribute__((address_space(1))) void*)(gA + (koff) + 32),               \
        (__attribute__((address_space(3))) void*)(base + 4096 + tid * 16), 16, 0, 0);    \
    __builtin_amdgcn_global_load_lds(                                                    \
        (const __attribute__((address_space(1))) void*)(gB + (koff)),                    \
        (__attribute__((address_space(3))) void*)(base + 8192 + tid * 16), 16, 0, 0);    \
    __builtin_amdgcn_global_load_lds(                                                    \
        (const __attribute__((address_space(1))) void*)(gB + (koff) + 32),               \
        (__attribute__((address_space(3))) void*)(base + 12288 + tid * 16), 16, 0, 0);   \
  } while (0)

#define COMPUTE(st)                                                                      \
  do {                                                                                   \
    const unsigned char* base = lds + (st) * 16384;                                      \
    _Pragma("unroll")                                                                    \
    for (int h = 0; h < 2; h++) {                                                        \
      const unsigned char* bA = base + h * 4096;                                         \
      const unsigned char* bB = base + 8192 + h * 4096;                                  \
      long long af[4], bf[4];                                                            \
      _Pragma("unroll")                                                                  \
      for (int mi = 0; mi < 4; mi++)                                                     \
        af[mi] = *(const long long*)(bA + (wr * 64 + mi * 16 + fr) * 32 + fc8);          \
      _Pragma("unroll")                                                                  \
      for (int ni = 0; ni < 4; ni++)                                                     \
        bf[ni] = *(const long long*)(bB + (wc * 64 + ni * 16 + fr) * 32 + fc8);          \
      _Pragma("unroll")                                                                  \
      for (int mi = 0; mi < 4; mi++)                                                     \
        _Pragma("unroll")                                                                \
        for (int ni = 0; ni < 4; ni++)                                                   \
          acc[mi][ni] = __builtin_amdgcn_mfma_f32_16x16x32_fp8_fp8(af[mi], bf[ni],       \
                                                                   acc[mi][ni], 0, 0, 0);\
    }                                                                                    \
  } while (0)

  ISSUE(0, 0);
  ISSUE(1, 64);
#pragma unroll 4
  for (int k = 0; k < KITER; k++) {
    const int cur = k % 3;
    if (k < KITER - 2) {
      ISSUE((k + 2) % 3, (k + 2) * 64);
      __builtin_amdgcn_s_waitcnt(WAITCNT_VM8);   // cur's 4 loads landed; 8 in flight
    } else if (k == KITER - 2) {
      __builtin_amdgcn_s_waitcnt(WAITCNT_VM4);
    } else {
      __builtin_amdgcn_s_waitcnt(WAITCNT_VM0);
    }
    __builtin_amdgcn_sched_barrier(0);
    __builtin_amdgcn_s_barrier();
    COMPUTE(cur);
    if (k < KITER - 1) {
      __builtin_amdgcn_s_barrier();
      __builtin_amdgcn_sched_barrier(0);
    }
  }

#undef ISSUE
#undef COMPUTE

  // Epilogue: partial = acc/256 (bf16), stored COL-MAJOR per tile (col*128 + row).
  unsigned short* dst = P + (size_t)(t * KSPLIT + kz) * 16384;
  const int cc  = lane & 15;
  const int cr4 = (lane >> 4) * 4;
#pragma unroll
  for (int mi = 0; mi < 4; mi++) {
    const int row = wr * 64 + mi * 16 + cr4;
#pragma unroll
    for (int ni = 0; ni < 4; ni++) {
      const int col = wc * 64 + ni * 16 + cc;
      unsigned int d0 = (unsigned int)f32_to_bf16(acc[mi][ni][0] * PART_SCALE) |
                        ((unsigned int)f32_to_bf16(acc[mi][ni][1] * PART_SCALE) << 16);
      unsigned int d1 = (unsigned int)f32_to_bf16(acc[mi][ni][2] * PART_SCALE) |
                        ((unsigned int)f32_to_bf16(acc[mi][ni][3] * PART_SCALE) << 16);
      uint2 v; v.x = d0; v.y = d1;
      *(uint2*)(dst + (size_t)col * 128 + row) = v;
    }
  }
}

// ---- Kernel 3A: combine partials (col-major) -> S (fp16, both triangles) + exp-rowsum T ----
__global__ __launch_bounds__(256) void k_combine(const unsigned short* __restrict__ P,
                                                 unsigned short* __restrict__ S,
                                                 float* __restrict__ T) {
  __shared__ float tileS[32][132];
  __shared__ float tileE[32][132];
  const int t = blockIdx.x;
  const int h = blockIdx.y;          // col quarter
  int ti = 0, rem = t;
  while (rem >= 16 - ti) { rem -= 16 - ti; ti++; }
  const int tj = ti + rem;
  const int gr = ti * 128, gc = tj * 128;
  const int c0 = h * 32;
  const int tid = threadIdx.x;
  const int cl = tid >> 3;           // local col 0..31
  const int q  = tid & 7;            // row chunk

  float acc[16];
#pragma unroll
  for (int j = 0; j < 16; j++) acc[j] = 0.f;
#pragma unroll
  for (int kz = 0; kz < KSPLIT; kz++) {
    const ushortx8* p = (const ushortx8*)(P + (size_t)(t * KSPLIT + kz) * 16384 +
                                          (size_t)(c0 + cl) * 128 + q * 16);
#pragma unroll
    for (int c = 0; c < 2; c++) {
      ushortx8 u = p[c];
#pragma unroll
      for (int e = 0; e < 8; e++) acc[c * 8 + e] += bf16_to_f32((unsigned short)u[e]);
    }
  }
  float cs = 0.f;
  unsigned short hv[16];
#pragma unroll
  for (int j = 0; j < 16; j++) {
    float v = acc[j] * INV_TEMP;
    float ev = __expf(v);
    hv[j] = f32_to_f16(v);
    tileS[cl][q * 16 + j] = v;
    tileE[cl][q * 16 + j] = ev;
    cs += ev;
  }
  // mirror write: S[gc+col][gr + q*16 .. +16]  (16 halfs = 2x uint4)
  {
    uint4* srow = (uint4*)(S + (size_t)(gc + c0 + cl) * NROWS + gr + q * 16);
#pragma unroll
    for (int u = 0; u < 2; u++) {
      uint4 w;
      w.x = (unsigned int)hv[u * 8 + 0] | ((unsigned int)hv[u * 8 + 1] << 16);
      w.y = (unsigned int)hv[u * 8 + 2] | ((unsigned int)hv[u * 8 + 3] << 16);
      w.z = (unsigned int)hv[u * 8 + 4] | ((unsigned int)hv[u * 8 + 5] << 16);
      w.w = (unsigned int)hv[u * 8 + 6] | ((unsigned int)hv[u * 8 + 7] << 16);
      srow[u] = w;
    }
  }
  cs += __shfl_xor(cs, 1, 64);
  cs += __shfl_xor(cs, 2, 64);
  cs += __shfl_xor(cs, 4, 64);
  if (q == 0) atomicAdd(&T[gc + c0 + cl], cs);

  if (ti != tj) {
    __syncthreads();
    const int r = tid >> 1;
    const int hh = tid & 1;
    float rs = 0.f;
    unsigned short hv2[16];
#pragma unroll
    for (int e = 0; e < 16; e++) {
      hv2[e] = f32_to_f16(tileS[hh * 16 + e][r]);
      rs += tileE[hh * 16 + e][r];
    }
    uint4* drow = (uint4*)(S + (size_t)(gr + r) * NROWS + gc + c0 + hh * 16);
#pragma unroll
    for (int u = 0; u < 2; u++) {
      uint4 w;
      w.x = (unsigned int)hv2[u * 8 + 0] | ((unsigned int)hv2[u * 8 + 1] << 16);
      w.y = (unsigned int)hv2[u * 8 + 2] | ((unsigned int)hv2[u * 8 + 3] << 16);
      w.z = (unsigned int)hv2[u * 8 + 4] | ((unsigned int)hv2[u * 8 + 5] << 16);
      w.w = (unsigned int)hv2[u * 8 + 6] | ((unsigned int)hv2[u * 8 + 7] << 16);
      drow[u] = w;
    }
    rs += __shfl_xor(rs, 1, 64);
    if (hh == 0) atomicAdd(&T[gr + r], rs);
  }
}

// ---- Kernel 4A: merged Dsum + pair losses (fp16 S). One wave per active row p. ----
__global__ __launch_bounds__(64) void k_tail(const unsigned short* __restrict__ S,
                                             const float* __restrict__ T,
                                             float* __restrict__ out) {
  const int p = blockIdx.x;
  const int a = 12 * (p >> 2) + (p & 3);
  const int lane = threadIdx.x;
  const int m = a >> 2;
  const int c = a & 3;
  __shared__ float Dsh[6];
#pragma unroll
  for (int k = 0; k < 6; k++) {
    const int row = (a + 4 * k) & (NROWS - 1);
    const uint2* sr = (const uint2*)(S + (size_t)row * NROWS);
    float s = 0.f;
    uint2 v0 = sr[(m + lane) & 511];
    uint2 v1 = sr[(m + 64 + lane) & 511];
    unsigned short e0 = (c < 2) ? (unsigned short)(v0.x >> (16 * c))
                                : (unsigned short)(v0.y >> (16 * (c - 2)));
    unsigned short e1 = (c < 2) ? (unsigned short)(v1.x >> (16 * c))
                                : (unsigned short)(v1.y >> (16 * (c - 2)));
    s += __expf(f16_to_f32(e0)) + __expf(f16_to_f32(e1));
    if (lane < 32) {
      uint2 v2 = sr[(m + 128 + lane) & 511];
      unsigned short e2 = (c < 2) ? (unsigned short)(v2.x >> (16 * c))
                                  : (unsigned short)(v2.y >> (16 * (c - 2)));
      s += __expf(f16_to_f32(e2));
    }
#pragma unroll
    for (int off = 32; off > 0; off >>= 1) s += __shfl_down(s, off, 64);
    if (lane == 0) Dsh[k] = T[row] - s;
  }
  __syncthreads();
  const int pa[7] = {0, 1, 0, 3, 4, 1, 2};
  const int pb[7] = {1, 2, 3, 4, 5, 4, 5};
  float s2 = 0.f;
  if (lane < 7) {
    const int ra = (a + 4 * pa[lane]) & (NROWS - 1);
    const int rb = (a + 4 * pb[lane]) & (NROWS - 1);
    const float num = f16_to_f32(S[(size_t)ra * NROWS + rb]);
    const float en = __expf(num);
    s2 = __logf(en + Dsh[pa[lane]]) + __logf(en + Dsh[pb[lane]]) - 2.f * num;
  }
#pragma unroll
  for (int off = 32; off > 0; off >>= 1) s2 += __shfl_down(s2, off, 64);
  if (lane == 0) atomicAdd(out, s2 * (1.0f / (6.0f * 512.0f)));
}

// ------------- Path B kernels (fallback when ws is small; fp32 S) -------------
__global__ __launch_bounds__(256) void k_normconv(const float* __restrict__ X,
                                                  unsigned short* __restrict__ Y) {
  const int row = blockIdx.x;
  const float4* xr = (const float4*)(X + (size_t)row * DIM);
  float4 v[4];
  float s = 0.f;
#pragma unroll
  for (int t = 0; t < 4; t++) {
    float4 w = xr[threadIdx.x + t * 256];
    v[t] = w;
    s += w.x * w.x + w.y * w.y + w.z * w.z + w.w * w.w;
  }
#pragma unroll
  for (int off = 32; off > 0; off >>= 1) s += __shfl_down(s, off, 64);
  __shared__ float wsum[4];
  if ((threadIdx.x & 63) == 0) wsum[threadIdx.x >> 6] = s;
  __syncthreads();
  const float total = wsum[0] + wsum[1] + wsum[2] + wsum[3];
  const float inv = 1.0f / fmaxf(sqrtf(total), 1e-30f);
  ushort4* yr = (ushort4*)(Y + (size_t)row * DIM);
#pragma unroll
  for (int t = 0; t < 4; t++) {
    float4 w = v[t];
    ushort4 o;
    o.x = f32_to_bf16(w.x * inv);
    o.y = f32_to_bf16(w.y * inv);
    o.z = f32_to_bf16(w.z * inv);
    o.w = f32_to_bf16(w.w * inv);
    yr[threadIdx.x + t * 256] = o;
  }
}

__global__ __launch_bounds__(256) void k_gemm(const unsigned short* __restrict__ Y,
                                              float* __restrict__ S) {
  __shared__ __attribute__((aligned(16))) unsigned short sA[128 * 32];
  __shared__ __attribute__((aligned(16))) unsigned short sB[128 * 32];
  const int tid  = threadIdx.x;
  const int lane = tid & 63;
  const int wave = tid >> 6;
  const int wr = wave >> 1;
  const int wc = wave & 1;
  const int row0 = blockIdx.y * 128;
  const int col0 = blockIdx.x * 128;

  floatx4 zero = {0.f, 0.f, 0.f, 0.f};
  floatx4 acc[4][4];
#pragma unroll
  for (int i = 0; i < 4; i++)
#pragma unroll
    for (int j = 0; j < 4; j++) acc[i][j] = zero;

  const int sr = tid >> 2;
  const int sc = (tid & 3) * 8;
  const unsigned short* gA0 = Y + (size_t)(row0 + sr) * DIM + sc;
  const unsigned short* gA1 = gA0 + (size_t)64 * DIM;
  const unsigned short* gB0 = Y + (size_t)(col0 + sr) * DIM + sc;
  const unsigned short* gB1 = gB0 + (size_t)64 * DIM;

  const int fr = lane & 15;
  const int fc = (lane >> 4) * 8;

  for (int k0 = 0; k0 < DIM; k0 += 32) {
    __builtin_amdgcn_global_load_lds(
        (const __attribute__((address_space(1))) void*)(gA0 + k0),
        (__attribute__((address_space(3))) void*)(sA + tid * 8), 16, 0, 0);
    __builtin_amdgcn_global_load_lds(
        (const __attribute__((address_space(1))) void*)(gA1 + k0),
        (__attribute__((address_space(3))) void*)(sA + 2048 + tid * 8), 16, 0, 0);
    __builtin_amdgcn_global_load_lds(
        (const __attribute__((address_space(1))) void*)(gB0 + k0),
        (__attribute__((address_space(3))) void*)(sB + tid * 8), 16, 0, 0);
    __builtin_amdgcn_global_load_lds(
        (const __attribute__((address_space(1))) void*)(gB1 + k0),
        (__attribute__((address_space(3))) void*)(sB + 2048 + tid * 8), 16, 0, 0);
    __syncthreads();

    shortx8 af[4], bf[4];
#pragma unroll
    for (int mi = 0; mi < 4; mi++)
      af[mi] = *(const shortx8*)(sA + (wr * 64 + mi * 16 + fr) * 32 + fc);
#pragma unroll
    for (int ni = 0; ni < 4; ni++)
      bf[ni] = *(const shortx8*)(sB + (wc * 64 + ni * 16 + fr) * 32 + fc);
#pragma unroll
    for (int mi = 0; mi < 4; mi++)
#pragma unroll
      for (int ni = 0; ni < 4; ni++)
        acc[mi][ni] = __builtin_amdgcn_mfma_f32_16x16x32_bf16(af[mi], bf[ni], acc[mi][ni], 0, 0, 0);
    __syncthreads();
  }

  const int cc  = lane & 15;
  const int cr4 = (lane >> 4) * 4;
#pragma unroll
  for (int mi = 0; mi < 4; mi++) {
    const int row = row0 + wr * 64 + mi * 16 + cr4;
#pragma unroll
    for (int ni = 0; ni < 4; ni++) {
      const int col = col0 + wc * 64 + ni * 16 + cc;
      float* dst = S + (size_t)row * NROWS + col;
#pragma unroll
      for (int r = 0; r < 4; r++) dst[(size_t)r * NROWS] = acc[mi][ni][r] * INV_TEMP;
    }
  }
}

__global__ __launch_bounds__(256) void k_rowsum(const float* __restrict__ S,
                                                float* __restrict__ T) {
  const int row = blockIdx.x;
  const float* sr = S + (size_t)row * NROWS;
  float s = 0.f;
  for (int b = threadIdx.x; b < NROWS; b += 256) s += __expf(sr[b]);
#pragma unroll
  for (int off = 32; off > 0; off >>= 1) s += __shfl_down(s, off, 64);
  __shared__ float wsum[4];
  if ((threadIdx.x & 63) == 0) wsum[threadIdx.x >> 6] = s;
  __syncthreads();
  if (threadIdx.x == 0) T[row] = wsum[0] + wsum[1] + wsum[2] + wsum[3];
}

__global__ __launch_bounds__(64) void k_dsum(const float* __restrict__ S,
                                             const float* __restrict__ T,
                                             float* __restrict__ Ds) {
  const int p = blockIdx.x;
  const int k = blockIdx.y;
  const int a = 12 * (p >> 2) + (p & 3);
  const int lane = threadIdx.x;
  const int row = (a + 4 * k) & (NROWS - 1);
  const int m = a >> 2;
  const int c = a & 3;
  const float4* sr4 = (const float4*)(S + (size_t)row * NROWS);
  float s = 0.f;
  {
    float4 v0 = sr4[(m + lane) & 511];
    float4 v1 = sr4[(m + 64 + lane) & 511];
    float e0 = c == 0 ? v0.x : c == 1 ? v0.y : c == 2 ? v0.z : v0.w;
    float e1 = c == 0 ? v1.x : c == 1 ? v1.y : c == 2 ? v1.z : v1.w;
    s += __expf(e0) + __expf(e1);
    if (lane < 32) {
      float4 v2 = sr4[(m + 128 + lane) & 511];
      float e2 = c == 0 ? v2.x : c == 1 ? v2.y : c == 2 ? v2.z : v2.w;
      s += __expf(e2);
    }
  }
#pragma unroll
  for (int off = 32; off > 0; off >>= 1) s += __shfl_down(s, off, 64);
  if (lane == 0) Ds[p * 6 + k] = T[row] - s;
}

__global__ __launch_bounds__(256) void k_final(const float* __restrict__ S,
                                               const float* __restrict__ Ds,
                                               float* __restrict__ out) {
  const int pa[7] = {0, 1, 0, 3, 4, 1, 2};
  const int pb[7] = {1, 2, 3, 4, 5, 4, 5};
  const int idx = blockIdx.x * 256 + threadIdx.x;
  float s = 0.f;
  if (idx < NACT * 7) {
    const int p = idx / 7;
    const int q = idx - p * 7;
    const int a0 = 12 * (p >> 2) + (p & 3);
    const int ra = (a0 + 4 * pa[q]) & (NROWS - 1);
    const int rb = (a0 + 4 * pb[q]) & (NROWS - 1);
    const float num = S[(size_t)ra * NROWS + rb];
    const float en = __expf(num);
    s = __logf(en + Ds[p * 6 + pa[q]]) + __logf(en + Ds[p * 6 + pb[q]]) - 2.f * num;
  }
#pragma unroll
  for (int off = 32; off > 0; off >>= 1) s += __shfl_down(s, off, 64);
  if ((threadIdx.x & 63) == 0) atomicAdd(out, s * (1.0f / (6.0f * 512.0f)));
}

extern "C" void kernel_launch(void* const* d_in, const int* in_sizes, int n_in,
                              void* d_out, int out_size, void* d_ws, size_t ws_size,
                              hipStream_t stream) {
  const float* X = (const float*)d_in[0];
  char* ws = (char*)d_ws;
  float* out = (float*)d_out;

  const size_t pOff = (size_t)32 * 1024 * 1024;
  const size_t pBytes = (size_t)NTILE * KSPLIT * 16384 * 2;     // 17.8 MB bf16 partials
  const size_t needA = pOff + pBytes + 8192 + 256;

  hipMemsetAsync(out, 0, sizeof(float), stream);

  if (ws_size >= needA) {
    unsigned char* Yq = (unsigned char*)ws;                       // 8 MB fp8
    unsigned short* S16 = (unsigned short*)(ws + (size_t)16 * 1024 * 1024); // 8 MB fp16
    unsigned short* P = (unsigned short*)(ws + pOff);
    float* T = (float*)(ws + pOff + pBytes);
    hipMemsetAsync(T, 0, NROWS * sizeof(float), stream);
    hipLaunchKernelGGL(k_normconv_fp8, dim3(NROWS), dim3(256), 0, stream, X, Yq);
    hipLaunchKernelGGL(k_gemm_sym, dim3(NTILE * KSPLIT), dim3(256), 0, stream, Yq, P);
    hipLaunchKernelGGL(k_combine, dim3(NTILE, 4), dim3(256), 0, stream, P, S16, T);
    hipLaunchKernelGGL(k_tail, dim3(NACT), dim3(64), 0, stream, S16, T, out);
  } else {
    unsigned short* Y = (unsigned short*)ws;                      // 16 MB bf16
    float* S = (float*)(ws + (size_t)16 * 1024 * 1024);           // 16 MB fp32
    float* T  = (float*)(ws + pOff);
    float* Ds = (float*)(ws + pOff + 8192);
    hipLaunchKernelGGL(k_normconv, dim3(NROWS), dim3(256), 0, stream, X, Y);
    hipLaunchKernelGGL(k_gemm, dim3(16, 16), dim3(256), 0, stream, Y, S);
    hipLaunchKernelGGL(k_rowsum, dim3(NROWS), dim3(256), 0, stream, S, T);
    hipLaunchKernelGGL(k_dsum, dim3(NACT, 6), dim3(64), 0, stream, S, T, Ds);
    hipLaunchKernelGGL(k_final, dim3((NACT * 7 + 255) / 256), dim3(256), 0, stream, S, Ds, out);
  }
}

// Round 12
// 123.068 us; speedup vs baseline: 1.2630x; 1.0446x over previous
//
#include <hip/hip_runtime.h>
#include <hip/hip_bf16.h>
#include <stdint.h>

#define NROWS 2048
#define DIM   4096
#define NACT  684
#define INV_TEMP 10.0f
#define NTILE 136        // 16*17/2 upper-triangle 128x128 tiles
#define KSPLIT 4
#define KSEG  1024       // DIM / KSPLIT
#define KITER 32         // KSEG / 32
#define FP8_SCALE 16.0f  // Y stored as fp8(y*16); dot = 256*cos
#define PART_SCALE (1.0f / 256.0f)

// s_waitcnt immediates (gfx9/CDNA: vmcnt[3:0]@0, expcnt@4, lgkmcnt@8, vmcnt[5:4]@14)
#define WAITCNT_VM0   0x0F70
#define WAITCNT_VM4   0x0F74
#define WAITCNT_VM8   0x0F78

typedef __attribute__((ext_vector_type(4))) float floatx4;
typedef __attribute__((ext_vector_type(8))) short shortx8;
typedef __attribute__((ext_vector_type(8))) unsigned short ushortx8;

static __device__ __forceinline__ unsigned short f32_to_bf16(float f) {
  union { float f; unsigned int u; } v; v.f = f;
  unsigned int u = v.u;
  unsigned int r = u + 0x7fffu + ((u >> 16) & 1u);
  return (unsigned short)(r >> 16);
}
static __device__ __forceinline__ float bf16_to_f32(unsigned short u) {
  union { unsigned int u; float f; } v; v.u = ((unsigned int)u) << 16;
  return v.f;
}
static __device__ __forceinline__ unsigned short f32_to_f16(float f) {
  _Float16 h = (_Float16)f;
  union { _Float16 h; unsigned short u; } v; v.h = h;
  return v.u;
}
static __device__ __forceinline__ float f16_to_f32(unsigned short u) {
  union { unsigned short u; _Float16 h; } v; v.u = u;
  return (float)v.h;
}

// ------- Kernel 1A: per-row L2 norm + fp8 e4m3 convert (y*16) -------
__global__ __launch_bounds__(256) void k_normconv_fp8(const float* __restrict__ X,
                                                      unsigned char* __restrict__ Yq) {
  const int row = blockIdx.x;
  const float4* xr = (const float4*)(X + (size_t)row * DIM);
  float4 v[4];
  float s = 0.f;
#pragma unroll
  for (int t = 0; t < 4; t++) {
    float4 w = xr[threadIdx.x * 4 + t];
    v[t] = w;
    s += w.x * w.x + w.y * w.y + w.z * w.z + w.w * w.w;
  }
#pragma unroll
  for (int off = 32; off > 0; off >>= 1) s += __shfl_down(s, off, 64);
  __shared__ float wsum[4];
  if ((threadIdx.x & 63) == 0) wsum[threadIdx.x >> 6] = s;
  __syncthreads();
  const float total = wsum[0] + wsum[1] + wsum[2] + wsum[3];
  const float sc = FP8_SCALE / fmaxf(sqrtf(total), 1e-30f);
  uint4 o;
  unsigned int r0;
  r0 = __builtin_amdgcn_cvt_pk_fp8_f32(v[0].x * sc, v[0].y * sc, 0, false);
  o.x = __builtin_amdgcn_cvt_pk_fp8_f32(v[0].z * sc, v[0].w * sc, r0, true);
  r0 = __builtin_amdgcn_cvt_pk_fp8_f32(v[1].x * sc, v[1].y * sc, 0, false);
  o.y = __builtin_amdgcn_cvt_pk_fp8_f32(v[1].z * sc, v[1].w * sc, r0, true);
  r0 = __builtin_amdgcn_cvt_pk_fp8_f32(v[2].x * sc, v[2].y * sc, 0, false);
  o.z = __builtin_amdgcn_cvt_pk_fp8_f32(v[2].z * sc, v[2].w * sc, r0, true);
  r0 = __builtin_amdgcn_cvt_pk_fp8_f32(v[3].x * sc, v[3].y * sc, 0, false);
  o.w = __builtin_amdgcn_cvt_pk_fp8_f32(v[3].z * sc, v[3].w * sc, r0, true);
  ((uint4*)(Yq + (size_t)row * DIM))[threadIdx.x] = o;
}

// ------- Kernel 2A: symmetric split-K(4) GEMM, fp8, BARRIER-FREE wave-private -------
// 3-stage per-wave pipeline. Each wave: 64x64 quadrant, private 12 KB slab
// (3 stages x (A 2KB + B 2KB)). Per iter: issue k+2's 4 loads -> vmcnt(8)
// (own iter-k loads landed; k+1,k+2 in flight) -> ds_read + 16 MFMA. No s_barrier.
// WAR safe: stage reuse is 3 iters behind; consuming MFMAs already executed.
__global__ __launch_bounds__(256) void k_gemm_sym(const unsigned char* __restrict__ Yq,
                                                  unsigned short* __restrict__ P) {
  __shared__ __attribute__((aligned(16))) unsigned char lds[4 * 12288]; // 4 waves x 3 x 4KB
  const int bid = blockIdx.x;
  const int kz = bid & 3;
  const int t  = bid >> 2;
  int ti = 0, rem = t;
  while (rem >= 16 - ti) { rem -= 16 - ti; ti++; }
  const int tj = ti + rem;
  const int kbase = kz * KSEG;

  const int tid  = threadIdx.x;
  const int lane = tid & 63;
  const int wave = tid >> 6;
  const int wr = wave >> 1;
  const int wc = wave & 1;
  const int row0 = ti * 128 + wr * 64;   // this wave's 64 A-rows
  const int col0 = tj * 128 + wc * 64;   // this wave's 64 B-rows

  unsigned char* wbase = lds + wave * 12288;

  floatx4 zero = {0.f, 0.f, 0.f, 0.f};
  floatx4 acc[4][4];
#pragma unroll
  for (int i = 0; i < 4; i++)
#pragma unroll
    for (int j = 0; j < 4; j++) acc[i][j] = zero;

  // staging: inst writes lane bytes [lane*16, +16): row lane>>1, col-half (lane&1)*16
  // of a 64x32 fp8 slab (row-major, 32 B/row); inst1 covers rows 32..63.
  const unsigned char* gA = Yq + (size_t)(row0 + (lane >> 1)) * DIM + kbase + (lane & 1) * 16;
  const unsigned char* gB = Yq + (size_t)(col0 + (lane >> 1)) * DIM + kbase + (lane & 1) * 16;

  const int fr  = lane & 15;
  const int fc8 = (lane >> 4) * 8;

#define ISSUE(st, koff)                                                                  \
  do {                                                                                   \
    unsigned char* sA = wbase + (st) * 4096;                                             \
    unsigned char* sB = sA + 2048;                                                       \
    __builtin_amdgcn_global_load_lds(                                                    \
        (const __attribute__((address_space(1))) void*)(gA + (koff)),                    \
        (__attribute__((address_space(3))) void*)(sA + lane * 16), 16, 0, 0);            \
    __builtin_amdgcn_global_load_lds(                                                    \
        (const __attribute__((address_space(1))) void*)(gA + (size_t)32 * DIM + (koff)), \
        (__attribute__((address_space(3))) void*)(sA + 1024 + lane * 16), 16, 0, 0);     \
    __builtin_amdgcn_global_load_lds(                                                    \
        (const __attribute__((address_space(1))) void*)(gB + (koff)),                    \
        (__attribute__((address_space(3))) void*)(sB + lane * 16), 16, 0, 0);            \
    __builtin_amdgcn_global_load_lds(                                                    \
        (const __attribute__((address_space(1))) void*)(gB + (size_t)32 * DIM + (koff)), \
        (__attribute__((address_space(3))) void*)(sB + 1024 + lane * 16), 16, 0, 0);     \
  } while (0)

#define COMPUTE(st)                                                                      \
  do {                                                                                   \
    const unsigned char* bA = wbase + (st) * 4096;                                       \
    const unsigned char* bB = bA + 2048;                                                 \
    long long af[4], bf[4];                                                              \
    _Pragma("unroll")                                                                    \
    for (int mi = 0; mi < 4; mi++)                                                       \
      af[mi] = *(const long long*)(bA + (mi * 16 + fr) * 32 + fc8);                      \
    _Pragma("unroll")                                                                    \
    for (int ni = 0; ni < 4; ni++)                                                       \
      bf[ni] = *(const long long*)(bB + (ni * 16 + fr) * 32 + fc8);                      \
    _Pragma("unroll")                                                                    \
    for (int mi = 0; mi < 4; mi++)                                                       \
      _Pragma("unroll")                                                                  \
      for (int ni = 0; ni < 4; ni++)                                                     \
        acc[mi][ni] = __builtin_amdgcn_mfma_f32_16x16x32_fp8_fp8(af[mi], bf[ni],         \
                                                                 acc[mi][ni], 0, 0, 0);  \
  } while (0)

  ISSUE(0, 0);
  ISSUE(1, 32);
#pragma unroll
  for (int k = 0; k < KITER; k++) {
    const int cur = k % 3;
    if (k < KITER - 2) {
      ISSUE((k + 2) % 3, (k + 2) * 32);
      __builtin_amdgcn_s_waitcnt(WAITCNT_VM8);   // own iter-k loads landed
    } else if (k == KITER - 2) {
      __builtin_amdgcn_s_waitcnt(WAITCNT_VM4);
    } else {
      __builtin_amdgcn_s_waitcnt(WAITCNT_VM0);
    }
    __builtin_amdgcn_sched_barrier(0);           // don't hoist ds_reads above the wait
    COMPUTE(cur);
  }

#undef ISSUE
#undef COMPUTE

  // Epilogue: partial = acc/256 (bf16), stored COL-MAJOR per tile (col*128 + row).
  unsigned short* dst = P + (size_t)(t * KSPLIT + kz) * 16384;
  const int cc  = lane & 15;
  const int cr4 = (lane >> 4) * 4;
#pragma unroll
  for (int mi = 0; mi < 4; mi++) {
    const int row = wr * 64 + mi * 16 + cr4;
#pragma unroll
    for (int ni = 0; ni < 4; ni++) {
      const int col = wc * 64 + ni * 16 + cc;
      unsigned int d0 = (unsigned int)f32_to_bf16(acc[mi][ni][0] * PART_SCALE) |
                        ((unsigned int)f32_to_bf16(acc[mi][ni][1] * PART_SCALE) << 16);
      unsigned int d1 = (unsigned int)f32_to_bf16(acc[mi][ni][2] * PART_SCALE) |
                        ((unsigned int)f32_to_bf16(acc[mi][ni][3] * PART_SCALE) << 16);
      uint2 v; v.x = d0; v.y = d1;
      *(uint2*)(dst + (size_t)col * 128 + row) = v;
    }
  }
}

// ---- Kernel 3A: combine partials (col-major) -> S (fp16, both triangles) + exp-rowsum T ----
__global__ __launch_bounds__(256) void k_combine(const unsigned short* __restrict__ P,
                                                 unsigned short* __restrict__ S,
                                                 float* __restrict__ T) {
  __shared__ float tileS[32][132];
  __shared__ float tileE[32][132];
  const int t = blockIdx.x;
  const int h = blockIdx.y;          // col quarter
  int ti = 0, rem = t;
  while (rem >= 16 - ti) { rem -= 16 - ti; ti++; }
  const int tj = ti + rem;
  const int gr = ti * 128, gc = tj * 128;
  const int c0 = h * 32;
  const int tid = threadIdx.x;
  const int cl = tid >> 3;           // local col 0..31
  const int q  = tid & 7;            // row chunk

  float acc[16];
#pragma unroll
  for (int j = 0; j < 16; j++) acc[j] = 0.f;
#pragma unroll
  for (int kz = 0; kz < KSPLIT; kz++) {
    const ushortx8* p = (const ushortx8*)(P + (size_t)(t * KSPLIT + kz) * 16384 +
                                          (size_t)(c0 + cl) * 128 + q * 16);
#pragma unroll
    for (int c = 0; c < 2; c++) {
      ushortx8 u = p[c];
#pragma unroll
      for (int e = 0; e < 8; e++) acc[c * 8 + e] += bf16_to_f32((unsigned short)u[e]);
    }
  }
  float cs = 0.f;
  unsigned short hv[16];
#pragma unroll
  for (int j = 0; j < 16; j++) {
    float v = acc[j] * INV_TEMP;
    float ev = __expf(v);
    hv[j] = f32_to_f16(v);
    tileS[cl][q * 16 + j] = v;
    tileE[cl][q * 16 + j] = ev;
    cs += ev;
  }
  // mirror write: S[gc+col][gr + q*16 .. +16]  (16 halfs = 2x uint4)
  {
    uint4* srow = (uint4*)(S + (size_t)(gc + c0 + cl) * NROWS + gr + q * 16);
#pragma unroll
    for (int u = 0; u < 2; u++) {
      uint4 w;
      w.x = (unsigned int)hv[u * 8 + 0] | ((unsigned int)hv[u * 8 + 1] << 16);
      w.y = (unsigned int)hv[u * 8 + 2] | ((unsigned int)hv[u * 8 + 3] << 16);
      w.z = (unsigned int)hv[u * 8 + 4] | ((unsigned int)hv[u * 8 + 5] << 16);
      w.w = (unsigned int)hv[u * 8 + 6] | ((unsigned int)hv[u * 8 + 7] << 16);
      srow[u] = w;
    }
  }
  cs += __shfl_xor(cs, 1, 64);
  cs += __shfl_xor(cs, 2, 64);
  cs += __shfl_xor(cs, 4, 64);
  if (q == 0) atomicAdd(&T[gc + c0 + cl], cs);

  if (ti != tj) {
    __syncthreads();
    const int r = tid >> 1;
    const int hh = tid & 1;
    float rs = 0.f;
    unsigned short hv2[16];
#pragma unroll
    for (int e = 0; e < 16; e++) {
      hv2[e] = f32_to_f16(tileS[hh * 16 + e][r]);
      rs += tileE[hh * 16 + e][r];
    }
    uint4* drow = (uint4*)(S + (size_t)(gr + r) * NROWS + gc + c0 + hh * 16);
#pragma unroll
    for (int u = 0; u < 2; u++) {
      uint4 w;
      w.x = (unsigned int)hv2[u * 8 + 0] | ((unsigned int)hv2[u * 8 + 1] << 16);
      w.y = (unsigned int)hv2[u * 8 + 2] | ((unsigned int)hv2[u * 8 + 3] << 16);
      w.z = (unsigned int)hv2[u * 8 + 4] | ((unsigned int)hv2[u * 8 + 5] << 16);
      w.w = (unsigned int)hv2[u * 8 + 6] | ((unsigned int)hv2[u * 8 + 7] << 16);
      drow[u] = w;
    }
    rs += __shfl_xor(rs, 1, 64);
    if (hh == 0) atomicAdd(&T[gr + r], rs);
  }
}

// ---- Kernel 4A: Dsum from fp16 S; coalesced uint2 gather ----
__global__ __launch_bounds__(64) void k_dsum_h(const unsigned short* __restrict__ S,
                                               const float* __restrict__ T,
                                               float* __restrict__ Ds) {
  const int p = blockIdx.x;
  const int k = blockIdx.y;
  const int a = 12 * (p >> 2) + (p & 3);
  const int lane = threadIdx.x;
  const int row = (a + 4 * k) & (NROWS - 1);
  const int m = a >> 2;
  const int c = a & 3;
  const uint2* sr = (const uint2*)(S + (size_t)row * NROWS);
  float s = 0.f;
  {
    uint2 v0 = sr[(m + lane) & 511];
    uint2 v1 = sr[(m + 64 + lane) & 511];
    unsigned short e0 = (c < 2) ? (unsigned short)(v0.x >> (16 * c))
                                : (unsigned short)(v0.y >> (16 * (c - 2)));
    unsigned short e1 = (c < 2) ? (unsigned short)(v1.x >> (16 * c))
                                : (unsigned short)(v1.y >> (16 * (c - 2)));
    s += __expf(f16_to_f32(e0)) + __expf(f16_to_f32(e1));
    if (lane < 32) {
      uint2 v2 = sr[(m + 128 + lane) & 511];
      unsigned short e2 = (c < 2) ? (unsigned short)(v2.x >> (16 * c))
                                  : (unsigned short)(v2.y >> (16 * (c - 2)));
      s += __expf(f16_to_f32(e2));
    }
  }
#pragma unroll
  for (int off = 32; off > 0; off >>= 1) s += __shfl_down(s, off, 64);
  if (lane == 0) Ds[p * 6 + k] = T[row] - s;
}

// ---------------- Kernel 5A: pair losses (fp16 S) ----------------
__global__ __launch_bounds__(256) void k_final_h(const unsigned short* __restrict__ S,
                                                 const float* __restrict__ Ds,
                                                 float* __restrict__ out) {
  const int pa[7] = {0, 1, 0, 3, 4, 1, 2};
  const int pb[7] = {1, 2, 3, 4, 5, 4, 5};
  const int idx = blockIdx.x * 256 + threadIdx.x;
  float s = 0.f;
  if (idx < NACT * 7) {
    const int p = idx / 7;
    const int q = idx - p * 7;
    const int a0 = 12 * (p >> 2) + (p & 3);
    const int ra = (a0 + 4 * pa[q]) & (NROWS - 1);
    const int rb = (a0 + 4 * pb[q]) & (NROWS - 1);
    const float num = f16_to_f32(S[(size_t)ra * NROWS + rb]);
    const float en = __expf(num);
    s = __logf(en + Ds[p * 6 + pa[q]]) + __logf(en + Ds[p * 6 + pb[q]]) - 2.f * num;
  }
#pragma unroll
  for (int off = 32; off > 0; off >>= 1) s += __shfl_down(s, off, 64);
  if ((threadIdx.x & 63) == 0) atomicAdd(out, s * (1.0f / (6.0f * 512.0f)));
}

// ------------- Path B kernels (fallback when ws is small; fp32 S) -------------
__global__ __launch_bounds__(256) void k_normconv(const float* __restrict__ X,
                                                  unsigned short* __restrict__ Y) {
  const int row = blockIdx.x;
  const float4* xr = (const float4*)(X + (size_t)row * DIM);
  float4 v[4];
  float s = 0.f;
#pragma unroll
  for (int t = 0; t < 4; t++) {
    float4 w = xr[threadIdx.x + t * 256];
    v[t] = w;
    s += w.x * w.x + w.y * w.y + w.z * w.z + w.w * w.w;
  }
#pragma unroll
  for (int off = 32; off > 0; off >>= 1) s += __shfl_down(s, off, 64);
  __shared__ float wsum[4];
  if ((threadIdx.x & 63) == 0) wsum[threadIdx.x >> 6] = s;
  __syncthreads();
  const float total = wsum[0] + wsum[1] + wsum[2] + wsum[3];
  const float inv = 1.0f / fmaxf(sqrtf(total), 1e-30f);
  ushort4* yr = (ushort4*)(Y + (size_t)row * DIM);
#pragma unroll
  for (int t = 0; t < 4; t++) {
    float4 w = v[t];
    ushort4 o;
    o.x = f32_to_bf16(w.x * inv);
    o.y = f32_to_bf16(w.y * inv);
    o.z = f32_to_bf16(w.z * inv);
    o.w = f32_to_bf16(w.w * inv);
    yr[threadIdx.x + t * 256] = o;
  }
}

__global__ __launch_bounds__(256) void k_gemm(const unsigned short* __restrict__ Y,
                                              float* __restrict__ S) {
  __shared__ __attribute__((aligned(16))) unsigned short sA[128 * 32];
  __shared__ __attribute__((aligned(16))) unsigned short sB[128 * 32];
  const int tid  = threadIdx.x;
  const int lane = tid & 63;
  const int wave = tid >> 6;
  const int wr = wave >> 1;
  const int wc = wave & 1;
  const int row0 = blockIdx.y * 128;
  const int col0 = blockIdx.x * 128;

  floatx4 zero = {0.f, 0.f, 0.f, 0.f};
  floatx4 acc[4][4];
#pragma unroll
  for (int i = 0; i < 4; i++)
#pragma unroll
    for (int j = 0; j < 4; j++) acc[i][j] = zero;

  const int sr = tid >> 2;
  const int sc = (tid & 3) * 8;
  const unsigned short* gA0 = Y + (size_t)(row0 + sr) * DIM + sc;
  const unsigned short* gA1 = gA0 + (size_t)64 * DIM;
  const unsigned short* gB0 = Y + (size_t)(col0 + sr) * DIM + sc;
  const unsigned short* gB1 = gB0 + (size_t)64 * DIM;

  const int fr = lane & 15;
  const int fc = (lane >> 4) * 8;

  for (int k0 = 0; k0 < DIM; k0 += 32) {
    __builtin_amdgcn_global_load_lds(
        (const __attribute__((address_space(1))) void*)(gA0 + k0),
        (__attribute__((address_space(3))) void*)(sA + tid * 8), 16, 0, 0);
    __builtin_amdgcn_global_load_lds(
        (const __attribute__((address_space(1))) void*)(gA1 + k0),
        (__attribute__((address_space(3))) void*)(sA + 2048 + tid * 8), 16, 0, 0);
    __builtin_amdgcn_global_load_lds(
        (const __attribute__((address_space(1))) void*)(gB0 + k0),
        (__attribute__((address_space(3))) void*)(sB + tid * 8), 16, 0, 0);
    __builtin_amdgcn_global_load_lds(
        (const __attribute__((address_space(1))) void*)(gB1 + k0),
        (__attribute__((address_space(3))) void*)(sB + 2048 + tid * 8), 16, 0, 0);
    __syncthreads();

    shortx8 af[4], bf[4];
#pragma unroll
    for (int mi = 0; mi < 4; mi++)
      af[mi] = *(const shortx8*)(sA + (wr * 64 + mi * 16 + fr) * 32 + fc);
#pragma unroll
    for (int ni = 0; ni < 4; ni++)
      bf[ni] = *(const shortx8*)(sB + (wc * 64 + ni * 16 + fr) * 32 + fc);
#pragma unroll
    for (int mi = 0; mi < 4; mi++)
#pragma unroll
      for (int ni = 0; ni < 4; ni++)
        acc[mi][ni] = __builtin_amdgcn_mfma_f32_16x16x32_bf16(af[mi], bf[ni], acc[mi][ni], 0, 0, 0);
    __syncthreads();
  }

  const int cc  = lane & 15;
  const int cr4 = (lane >> 4) * 4;
#pragma unroll
  for (int mi = 0; mi < 4; mi++) {
    const int row = row0 + wr * 64 + mi * 16 + cr4;
#pragma unroll
    for (int ni = 0; ni < 4; ni++) {
      const int col = col0 + wc * 64 + ni * 16 + cc;
      float* dst = S + (size_t)row * NROWS + col;
#pragma unroll
      for (int r = 0; r < 4; r++) dst[(size_t)r * NROWS] = acc[mi][ni][r] * INV_TEMP;
    }
  }
}

__global__ __launch_bounds__(256) void k_rowsum(const float* __restrict__ S,
                                                float* __restrict__ T) {
  const int row = blockIdx.x;
  const float* sr = S + (size_t)row * NROWS;
  float s = 0.f;
  for (int b = threadIdx.x; b < NROWS; b += 256) s += __expf(sr[b]);
#pragma unroll
  for (int off = 32; off > 0; off >>= 1) s += __shfl_down(s, off, 64);
  __shared__ float wsum[4];
  if ((threadIdx.x & 63) == 0) wsum[threadIdx.x >> 6] = s;
  __syncthreads();
  if (threadIdx.x == 0) T[row] = wsum[0] + wsum[1] + wsum[2] + wsum[3];
}

__global__ __launch_bounds__(64) void k_dsum(const float* __restrict__ S,
                                             const float* __restrict__ T,
                                             float* __restrict__ Ds) {
  const int p = blockIdx.x;
  const int k = blockIdx.y;
  const int a = 12 * (p >> 2) + (p & 3);
  const int lane = threadIdx.x;
  const int row = (a + 4 * k) & (NROWS - 1);
  const int m = a >> 2;
  const int c = a & 3;
  const float4* sr4 = (const float4*)(S + (size_t)row * NROWS);
  float s = 0.f;
  {
    float4 v0 = sr4[(m + lane) & 511];
    float4 v1 = sr4[(m + 64 + lane) & 511];
    float e0 = c == 0 ? v0.x : c == 1 ? v0.y : c == 2 ? v0.z : v0.w;
    float e1 = c == 0 ? v1.x : c == 1 ? v1.y : c == 2 ? v1.z : v1.w;
    s += __expf(e0) + __expf(e1);
    if (lane < 32) {
      float4 v2 = sr4[(m + 128 + lane) & 511];
      float e2 = c == 0 ? v2.x : c == 1 ? v2.y : c == 2 ? v2.z : v2.w;
      s += __expf(e2);
    }
  }
#pragma unroll
  for (int off = 32; off > 0; off >>= 1) s += __shfl_down(s, off, 64);
  if (lane == 0) Ds[p * 6 + k] = T[row] - s;
}

__global__ __launch_bounds__(256) void k_final(const float* __restrict__ S,
                                               const float* __restrict__ Ds,
                                               float* __restrict__ out) {
  const int pa[7] = {0, 1, 0, 3, 4, 1, 2};
  const int pb[7] = {1, 2, 3, 4, 5, 4, 5};
  const int idx = blockIdx.x * 256 + threadIdx.x;
  float s = 0.f;
  if (idx < NACT * 7) {
    const int p = idx / 7;
    const int q = idx - p * 7;
    const int a0 = 12 * (p >> 2) + (p & 3);
    const int ra = (a0 + 4 * pa[q]) & (NROWS - 1);
    const int rb = (a0 + 4 * pb[q]) & (NROWS - 1);
    const float num = S[(size_t)ra * NROWS + rb];
    const float en = __expf(num);
    s = __logf(en + Ds[p * 6 + pa[q]]) + __logf(en + Ds[p * 6 + pb[q]]) - 2.f * num;
  }
#pragma unroll
  for (int off = 32; off > 0; off >>= 1) s += __shfl_down(s, off, 64);
  if ((threadIdx.x & 63) == 0) atomicAdd(out, s * (1.0f / (6.0f * 512.0f)));
}

extern "C" void kernel_launch(void* const* d_in, const int* in_sizes, int n_in,
                              void* d_out, int out_size, void* d_ws, size_t ws_size,
                              hipStream_t stream) {
  const float* X = (const float*)d_in[0];
  char* ws = (char*)d_ws;
  float* out = (float*)d_out;

  const size_t pOff = (size_t)32 * 1024 * 1024;
  const size_t pBytes = (size_t)NTILE * KSPLIT * 16384 * 2;     // 17.8 MB bf16 partials
  const size_t needA = pOff + pBytes + 8192 + NACT * 6 * 4 + 256;

  hipMemsetAsync(out, 0, sizeof(float), stream);

  if (ws_size >= needA) {
    unsigned char* Yq = (unsigned char*)ws;                       // 8 MB fp8
    unsigned short* S16 = (unsigned short*)(ws + (size_t)16 * 1024 * 1024); // 8 MB fp16
    unsigned short* P = (unsigned short*)(ws + pOff);
    float* T  = (float*)(ws + pOff + pBytes);
    float* Ds = (float*)(ws + pOff + pBytes + 8192);
    hipMemsetAsync(T, 0, NROWS * sizeof(float), stream);
    hipLaunchKernelGGL(k_normconv_fp8, dim3(NROWS), dim3(256), 0, stream, X, Yq);
    hipLaunchKernelGGL(k_gemm_sym, dim3(NTILE * KSPLIT), dim3(256), 0, stream, Yq, P);
    hipLaunchKernelGGL(k_combine, dim3(NTILE, 4), dim3(256), 0, stream, P, S16, T);
    hipLaunchKernelGGL(k_dsum_h, dim3(NACT, 6), dim3(64), 0, stream, S16, T, Ds);
    hipLaunchKernelGGL(k_final_h, dim3((NACT * 7 + 255) / 256), dim3(256), 0, stream, S16, Ds, out);
  } else {
    unsigned short* Y = (unsigned short*)ws;                      // 16 MB bf16
    float* S = (float*)(ws + (size_t)16 * 1024 * 1024);           // 16 MB fp32
    float* T  = (float*)(ws + pOff);
    float* Ds = (float*)(ws + pOff + 8192);
    hipLaunchKernelGGL(k_normconv, dim3(NROWS), dim3(256), 0, stream, X, Y);
    hipLaunchKernelGGL(k_gemm, dim3(16, 16), dim3(256), 0, stream, Y, S);
    hipLaunchKernelGGL(k_rowsum, dim3(NROWS), dim3(256), 0, stream, S, T);
    hipLaunchKernelGGL(k_dsum, dim3(NACT, 6), dim3(64), 0, stream, S, T, Ds);
    hipLaunchKernelGGL(k_final, dim3((NACT * 7 + 255) / 256), dim3(256), 0, stream, S, Ds, out);
  }
}

// Round 13
// 120.758 us; speedup vs baseline: 1.2872x; 1.0191x over previous
//
#include <hip/hip_runtime.h>
#include <hip/hip_bf16.h>
#include <stdint.h>

#define NROWS 2048
#define DIM   4096
#define NACT  684
#define INV_TEMP 10.0f
#define NTILE 136        // 16*17/2 upper-triangle 128x128 tiles
#define KSPLIT 4
#define KSEG  1024       // DIM / KSPLIT
#define KITER 32         // KSEG / 32
#define FP8_SCALE 16.0f  // Y stored as fp8(y*16); dot = 256*cos
#define PART_SCALE (1.0f / 256.0f)

// s_waitcnt immediates (gfx9/CDNA: vmcnt[3:0]@0, expcnt@4, lgkmcnt@8, vmcnt[5:4]@14)
#define WAITCNT_VM0   0x0F70
#define WAITCNT_VM2   0x0F72
#define WAITCNT_VM4   0x0F74
#define WAITCNT_VM6   0x0F76

typedef __attribute__((ext_vector_type(4))) float floatx4;
typedef __attribute__((ext_vector_type(8))) short shortx8;
typedef __attribute__((ext_vector_type(8))) unsigned short ushortx8;

static __device__ __forceinline__ unsigned short f32_to_bf16(float f) {
  union { float f; unsigned int u; } v; v.f = f;
  unsigned int u = v.u;
  unsigned int r = u + 0x7fffu + ((u >> 16) & 1u);
  return (unsigned short)(r >> 16);
}
static __device__ __forceinline__ float bf16_to_f32(unsigned short u) {
  union { unsigned int u; float f; } v; v.u = ((unsigned int)u) << 16;
  return v.f;
}
static __device__ __forceinline__ unsigned short f32_to_f16(float f) {
  _Float16 h = (_Float16)f;
  union { _Float16 h; unsigned short u; } v; v.h = h;
  return v.u;
}
static __device__ __forceinline__ float f16_to_f32(unsigned short u) {
  union { unsigned short u; _Float16 h; } v; v.u = u;
  return (float)v.h;
}

// ------- Kernel 1A: per-row L2 norm + fp8 e4m3 convert (y*16) -------
__global__ __launch_bounds__(256) void k_normconv_fp8(const float* __restrict__ X,
                                                      unsigned char* __restrict__ Yq) {
  const int row = blockIdx.x;
  const float4* xr = (const float4*)(X + (size_t)row * DIM);
  float4 v[4];
  float s = 0.f;
#pragma unroll
  for (int t = 0; t < 4; t++) {
    float4 w = xr[threadIdx.x * 4 + t];
    v[t] = w;
    s += w.x * w.x + w.y * w.y + w.z * w.z + w.w * w.w;
  }
#pragma unroll
  for (int off = 32; off > 0; off >>= 1) s += __shfl_down(s, off, 64);
  __shared__ float wsum[4];
  if ((threadIdx.x & 63) == 0) wsum[threadIdx.x >> 6] = s;
  __syncthreads();
  const float total = wsum[0] + wsum[1] + wsum[2] + wsum[3];
  const float sc = FP8_SCALE / fmaxf(sqrtf(total), 1e-30f);
  uint4 o;
  unsigned int r0;
  r0 = __builtin_amdgcn_cvt_pk_fp8_f32(v[0].x * sc, v[0].y * sc, 0, false);
  o.x = __builtin_amdgcn_cvt_pk_fp8_f32(v[0].z * sc, v[0].w * sc, r0, true);
  r0 = __builtin_amdgcn_cvt_pk_fp8_f32(v[1].x * sc, v[1].y * sc, 0, false);
  o.y = __builtin_amdgcn_cvt_pk_fp8_f32(v[1].z * sc, v[1].w * sc, r0, true);
  r0 = __builtin_amdgcn_cvt_pk_fp8_f32(v[2].x * sc, v[2].y * sc, 0, false);
  o.z = __builtin_amdgcn_cvt_pk_fp8_f32(v[2].z * sc, v[2].w * sc, r0, true);
  r0 = __builtin_amdgcn_cvt_pk_fp8_f32(v[3].x * sc, v[3].y * sc, 0, false);
  o.w = __builtin_amdgcn_cvt_pk_fp8_f32(v[3].z * sc, v[3].w * sc, r0, true);
  ((uint4*)(Yq + (size_t)row * DIM))[threadIdx.x] = o;
}

// ------- Kernel 2A: symmetric split-K(4) GEMM, fp8, 4-stage pipeline -------
__global__ __launch_bounds__(256) void k_gemm_sym(const unsigned char* __restrict__ Yq,
                                                  unsigned short* __restrict__ P) {
  __shared__ __attribute__((aligned(16))) unsigned char lds[4 * 8192];
  const int bid = blockIdx.x;
  const int kz = bid & 3;
  const int t  = bid >> 2;
  int ti = 0, rem = t;
  while (rem >= 16 - ti) { rem -= 16 - ti; ti++; }
  const int tj = ti + rem;
  const int row0 = ti * 128;
  const int col0 = tj * 128;
  const int kbase = kz * KSEG;

  const int tid  = threadIdx.x;
  const int lane = tid & 63;
  const int wave = tid >> 6;
  const int wr = wave >> 1;
  const int wc = wave & 1;

  floatx4 zero = {0.f, 0.f, 0.f, 0.f};
  floatx4 acc[4][4];
#pragma unroll
  for (int i = 0; i < 4; i++)
#pragma unroll
    for (int j = 0; j < 4; j++) acc[i][j] = zero;

  // staging: thread t covers LDS bytes [16t,16t+16) = row (t>>1), colbytes (t&1)*16
  const unsigned char* gA = Yq + (size_t)(row0 + (tid >> 1)) * DIM + kbase + (tid & 1) * 16;
  const unsigned char* gB = Yq + (size_t)(col0 + (tid >> 1)) * DIM + kbase + (tid & 1) * 16;

  const int fr  = lane & 15;
  const int fc8 = (lane >> 4) * 8;

#define ISSUE(st, koff)                                                                \
  do {                                                                                 \
    __builtin_amdgcn_global_load_lds(                                                  \
        (const __attribute__((address_space(1))) void*)(gA + (koff)),                  \
        (__attribute__((address_space(3))) void*)(lds + (st) * 8192 + tid * 16),       \
        16, 0, 0);                                                                     \
    __builtin_amdgcn_global_load_lds(                                                  \
        (const __attribute__((address_space(1))) void*)(gB + (koff)),                  \
        (__attribute__((address_space(3))) void*)(lds + (st) * 8192 + 4096 + tid * 16),\
        16, 0, 0);                                                                     \
  } while (0)

#define COMPUTE(st)                                                                    \
  do {                                                                                 \
    const unsigned char* bA = lds + (st) * 8192;                                       \
    const unsigned char* bB = bA + 4096;                                               \
    long long af[4], bf[4];                                                            \
    _Pragma("unroll")                                                                  \
    for (int mi = 0; mi < 4; mi++)                                                     \
      af[mi] = *(const long long*)(bA + (wr * 64 + mi * 16 + fr) * 32 + fc8);          \
    _Pragma("unroll")                                                                  \
    for (int ni = 0; ni < 4; ni++)                                                     \
      bf[ni] = *(const long long*)(bB + (wc * 64 + ni * 16 + fr) * 32 + fc8);          \
    _Pragma("unroll")                                                                  \
    for (int mi = 0; mi < 4; mi++)                                                     \
      _Pragma("unroll")                                                                \
      for (int ni = 0; ni < 4; ni++)                                                   \
        acc[mi][ni] = __builtin_amdgcn_mfma_f32_16x16x32_fp8_fp8(af[mi], bf[ni],       \
                                                                 acc[mi][ni], 0, 0, 0);\
  } while (0)

  ISSUE(0, 0);
  ISSUE(1, 32);
  ISSUE(2, 64);
#pragma unroll 4
  for (int k = 0; k < KITER; k++) {
    const int cur = k & 3;
    if (k < KITER - 3) {
      ISSUE((k + 3) & 3, (k + 3) * 32);
      __builtin_amdgcn_s_waitcnt(WAITCNT_VM6);
    } else if (k == KITER - 3) {
      __builtin_amdgcn_s_waitcnt(WAITCNT_VM4);
    } else if (k == KITER - 2) {
      __builtin_amdgcn_s_waitcnt(WAITCNT_VM2);
    } else {
      __builtin_amdgcn_s_waitcnt(WAITCNT_VM0);
    }
    __builtin_amdgcn_sched_barrier(0);
    __builtin_amdgcn_s_barrier();
    COMPUTE(cur);
    if (k < KITER - 1) {
      __builtin_amdgcn_s_barrier();
      __builtin_amdgcn_sched_barrier(0);
    }
  }

#undef ISSUE
#undef COMPUTE

  // Epilogue: partial = acc/256 (bf16), stored COL-MAJOR per tile (col*128 + row).
  unsigned short* dst = P + (size_t)(t * KSPLIT + kz) * 16384;
  const int cc  = lane & 15;
  const int cr4 = (lane >> 4) * 4;
#pragma unroll
  for (int mi = 0; mi < 4; mi++) {
    const int row = wr * 64 + mi * 16 + cr4;
#pragma unroll
    for (int ni = 0; ni < 4; ni++) {
      const int col = wc * 64 + ni * 16 + cc;
      unsigned int d0 = (unsigned int)f32_to_bf16(acc[mi][ni][0] * PART_SCALE) |
                        ((unsigned int)f32_to_bf16(acc[mi][ni][1] * PART_SCALE) << 16);
      unsigned int d1 = (unsigned int)f32_to_bf16(acc[mi][ni][2] * PART_SCALE) |
                        ((unsigned int)f32_to_bf16(acc[mi][ni][3] * PART_SCALE) << 16);
      uint2 v; v.x = d0; v.y = d1;
      *(uint2*)(dst + (size_t)col * 128 + row) = v;
    }
  }
}

// ---- Kernel 3A: combine partials (col-major) -> S (fp16, both triangles) + exp-rowsum T ----
__global__ __launch_bounds__(256) void k_combine(const unsigned short* __restrict__ P,
                                                 unsigned short* __restrict__ S,
                                                 float* __restrict__ T) {
  __shared__ float tileS[32][132];
  __shared__ float tileE[32][132];
  const int t = blockIdx.x;
  const int h = blockIdx.y;          // col quarter
  int ti = 0, rem = t;
  while (rem >= 16 - ti) { rem -= 16 - ti; ti++; }
  const int tj = ti + rem;
  const int gr = ti * 128, gc = tj * 128;
  const int c0 = h * 32;
  const int tid = threadIdx.x;
  const int cl = tid >> 3;           // local col 0..31
  const int q  = tid & 7;            // row chunk

  float acc[16];
#pragma unroll
  for (int j = 0; j < 16; j++) acc[j] = 0.f;
#pragma unroll
  for (int kz = 0; kz < KSPLIT; kz++) {
    const ushortx8* p = (const ushortx8*)(P + (size_t)(t * KSPLIT + kz) * 16384 +
                                          (size_t)(c0 + cl) * 128 + q * 16);
#pragma unroll
    for (int c = 0; c < 2; c++) {
      ushortx8 u = p[c];
#pragma unroll
      for (int e = 0; e < 8; e++) acc[c * 8 + e] += bf16_to_f32((unsigned short)u[e]);
    }
  }
  float cs = 0.f;
  unsigned short hv[16];
#pragma unroll
  for (int j = 0; j < 16; j++) {
    float v = acc[j] * INV_TEMP;
    float ev = __expf(v);
    hv[j] = f32_to_f16(v);
    tileS[cl][q * 16 + j] = v;
    tileE[cl][q * 16 + j] = ev;
    cs += ev;
  }
  // mirror write: S[gc+col][gr + q*16 .. +16]  (16 halfs = 2x uint4)
  {
    uint4* srow = (uint4*)(S + (size_t)(gc + c0 + cl) * NROWS + gr + q * 16);
#pragma unroll
    for (int u = 0; u < 2; u++) {
      uint4 w;
      w.x = (unsigned int)hv[u * 8 + 0] | ((unsigned int)hv[u * 8 + 1] << 16);
      w.y = (unsigned int)hv[u * 8 + 2] | ((unsigned int)hv[u * 8 + 3] << 16);
      w.z = (unsigned int)hv[u * 8 + 4] | ((unsigned int)hv[u * 8 + 5] << 16);
      w.w = (unsigned int)hv[u * 8 + 6] | ((unsigned int)hv[u * 8 + 7] << 16);
      srow[u] = w;
    }
  }
  cs += __shfl_xor(cs, 1, 64);
  cs += __shfl_xor(cs, 2, 64);
  cs += __shfl_xor(cs, 4, 64);
  if (q == 0) atomicAdd(&T[gc + c0 + cl], cs);

  if (ti != tj) {
    __syncthreads();
    const int r = tid >> 1;
    const int hh = tid & 1;
    float rs = 0.f;
    unsigned short hv2[16];
#pragma unroll
    for (int e = 0; e < 16; e++) {
      hv2[e] = f32_to_f16(tileS[hh * 16 + e][r]);
      rs += tileE[hh * 16 + e][r];
    }
    uint4* drow = (uint4*)(S + (size_t)(gr + r) * NROWS + gc + c0 + hh * 16);
#pragma unroll
    for (int u = 0; u < 2; u++) {
      uint4 w;
      w.x = (unsigned int)hv2[u * 8 + 0] | ((unsigned int)hv2[u * 8 + 1] << 16);
      w.y = (unsigned int)hv2[u * 8 + 2] | ((unsigned int)hv2[u * 8 + 3] << 16);
      w.z = (unsigned int)hv2[u * 8 + 4] | ((unsigned int)hv2[u * 8 + 5] << 16);
      w.w = (unsigned int)hv2[u * 8 + 6] | ((unsigned int)hv2[u * 8 + 7] << 16);
      drow[u] = w;
    }
    rs += __shfl_xor(rs, 1, 64);
    if (hh == 0) atomicAdd(&T[gr + r], rs);
  }
}

// ---- Kernel 4A: Dsum from fp16 S; coalesced uint2 gather (4 halfs, stride-4 cols) ----
__global__ __launch_bounds__(64) void k_dsum_h(const unsigned short* __restrict__ S,
                                               const float* __restrict__ T,
                                               float* __restrict__ Ds) {
  const int p = blockIdx.x;
  const int k = blockIdx.y;
  const int a = 12 * (p >> 2) + (p & 3);
  const int lane = threadIdx.x;
  const int row = (a + 4 * k) & (NROWS - 1);
  const int m = a >> 2;
  const int c = a & 3;
  const uint2* sr = (const uint2*)(S + (size_t)row * NROWS);
  float s = 0.f;
  {
    uint2 v0 = sr[(m + lane) & 511];
    uint2 v1 = sr[(m + 64 + lane) & 511];
    unsigned short e0 = (c < 2) ? (unsigned short)(v0.x >> (16 * c))
                                : (unsigned short)(v0.y >> (16 * (c - 2)));
    unsigned short e1 = (c < 2) ? (unsigned short)(v1.x >> (16 * c))
                                : (unsigned short)(v1.y >> (16 * (c - 2)));
    s += __expf(f16_to_f32(e0)) + __expf(f16_to_f32(e1));
    if (lane < 32) {
      uint2 v2 = sr[(m + 128 + lane) & 511];
      unsigned short e2 = (c < 2) ? (unsigned short)(v2.x >> (16 * c))
                                  : (unsigned short)(v2.y >> (16 * (c - 2)));
      s += __expf(f16_to_f32(e2));
    }
  }
#pragma unroll
  for (int off = 32; off > 0; off >>= 1) s += __shfl_down(s, off, 64);
  if (lane == 0) Ds[p * 6 + k] = T[row] - s;
}

// ---------------- Kernel 5A: pair losses (fp16 S) ----------------
__global__ __launch_bounds__(256) void k_final_h(const unsigned short* __restrict__ S,
                                                 const float* __restrict__ Ds,
                                                 float* __restrict__ out) {
  const int pa[7] = {0, 1, 0, 3, 4, 1, 2};
  const int pb[7] = {1, 2, 3, 4, 5, 4, 5};
  const int idx = blockIdx.x * 256 + threadIdx.x;
  float s = 0.f;
  if (idx < NACT * 7) {
    const int p = idx / 7;
    const int q = idx - p * 7;
    const int a0 = 12 * (p >> 2) + (p & 3);
    const int ra = (a0 + 4 * pa[q]) & (NROWS - 1);
    const int rb = (a0 + 4 * pb[q]) & (NROWS - 1);
    const float num = f16_to_f32(S[(size_t)ra * NROWS + rb]);
    const float en = __expf(num);
    s = __logf(en + Ds[p * 6 + pa[q]]) + __logf(en + Ds[p * 6 + pb[q]]) - 2.f * num;
  }
#pragma unroll
  for (int off = 32; off > 0; off >>= 1) s += __shfl_down(s, off, 64);
  if ((threadIdx.x & 63) == 0) atomicAdd(out, s * (1.0f / (6.0f * 512.0f)));
}

// ------------- Path B kernels (fallback when ws is small; fp32 S) -------------
__global__ __launch_bounds__(256) void k_normconv(const float* __restrict__ X,
                                                  unsigned short* __restrict__ Y) {
  const int row = blockIdx.x;
  const float4* xr = (const float4*)(X + (size_t)row * DIM);
  float4 v[4];
  float s = 0.f;
#pragma unroll
  for (int t = 0; t < 4; t++) {
    float4 w = xr[threadIdx.x + t * 256];
    v[t] = w;
    s += w.x * w.x + w.y * w.y + w.z * w.z + w.w * w.w;
  }
#pragma unroll
  for (int off = 32; off > 0; off >>= 1) s += __shfl_down(s, off, 64);
  __shared__ float wsum[4];
  if ((threadIdx.x & 63) == 0) wsum[threadIdx.x >> 6] = s;
  __syncthreads();
  const float total = wsum[0] + wsum[1] + wsum[2] + wsum[3];
  const float inv = 1.0f / fmaxf(sqrtf(total), 1e-30f);
  ushort4* yr = (ushort4*)(Y + (size_t)row * DIM);
#pragma unroll
  for (int t = 0; t < 4; t++) {
    float4 w = v[t];
    ushort4 o;
    o.x = f32_to_bf16(w.x * inv);
    o.y = f32_to_bf16(w.y * inv);
    o.z = f32_to_bf16(w.z * inv);
    o.w = f32_to_bf16(w.w * inv);
    yr[threadIdx.x + t * 256] = o;
  }
}

__global__ __launch_bounds__(256) void k_gemm(const unsigned short* __restrict__ Y,
                                              float* __restrict__ S) {
  __shared__ __attribute__((aligned(16))) unsigned short sA[128 * 32];
  __shared__ __attribute__((aligned(16))) unsigned short sB[128 * 32];
  const int tid  = threadIdx.x;
  const int lane = tid & 63;
  const int wave = tid >> 6;
  const int wr = wave >> 1;
  const int wc = wave & 1;
  const int row0 = blockIdx.y * 128;
  const int col0 = blockIdx.x * 128;

  floatx4 zero = {0.f, 0.f, 0.f, 0.f};
  floatx4 acc[4][4];
#pragma unroll
  for (int i = 0; i < 4; i++)
#pragma unroll
    for (int j = 0; j < 4; j++) acc[i][j] = zero;

  const int sr = tid >> 2;
  const int sc = (tid & 3) * 8;
  const unsigned short* gA0 = Y + (size_t)(row0 + sr) * DIM + sc;
  const unsigned short* gA1 = gA0 + (size_t)64 * DIM;
  const unsigned short* gB0 = Y + (size_t)(col0 + sr) * DIM + sc;
  const unsigned short* gB1 = gB0 + (size_t)64 * DIM;

  const int fr = lane & 15;
  const int fc = (lane >> 4) * 8;

  for (int k0 = 0; k0 < DIM; k0 += 32) {
    __builtin_amdgcn_global_load_lds(
        (const __attribute__((address_space(1))) void*)(gA0 + k0),
        (__attribute__((address_space(3))) void*)(sA + tid * 8), 16, 0, 0);
    __builtin_amdgcn_global_load_lds(
        (const __attribute__((address_space(1))) void*)(gA1 + k0),
        (__attribute__((address_space(3))) void*)(sA + 2048 + tid * 8), 16, 0, 0);
    __builtin_amdgcn_global_load_lds(
        (const __attribute__((address_space(1))) void*)(gB0 + k0),
        (__attribute__((address_space(3))) void*)(sB + tid * 8), 16, 0, 0);
    __builtin_amdgcn_global_load_lds(
        (const __attribute__((address_space(1))) void*)(gB1 + k0),
        (__attribute__((address_space(3))) void*)(sB + 2048 + tid * 8), 16, 0, 0);
    __syncthreads();

    shortx8 af[4], bf[4];
#pragma unroll
    for (int mi = 0; mi < 4; mi++)
      af[mi] = *(const shortx8*)(sA + (wr * 64 + mi * 16 + fr) * 32 + fc);
#pragma unroll
    for (int ni = 0; ni < 4; ni++)
      bf[ni] = *(const shortx8*)(sB + (wc * 64 + ni * 16 + fr) * 32 + fc);
#pragma unroll
    for (int mi = 0; mi < 4; mi++)
#pragma unroll
      for (int ni = 0; ni < 4; ni++)
        acc[mi][ni] = __builtin_amdgcn_mfma_f32_16x16x32_bf16(af[mi], bf[ni], acc[mi][ni], 0, 0, 0);
    __syncthreads();
  }

  const int cc  = lane & 15;
  const int cr4 = (lane >> 4) * 4;
#pragma unroll
  for (int mi = 0; mi < 4; mi++) {
    const int row = row0 + wr * 64 + mi * 16 + cr4;
#pragma unroll
    for (int ni = 0; ni < 4; ni++) {
      const int col = col0 + wc * 64 + ni * 16 + cc;
      float* dst = S + (size_t)row * NROWS + col;
#pragma unroll
      for (int r = 0; r < 4; r++) dst[(size_t)r * NROWS] = acc[mi][ni][r] * INV_TEMP;
    }
  }
}

__global__ __launch_bounds__(256) void k_rowsum(const float* __restrict__ S,
                                                float* __restrict__ T) {
  const int row = blockIdx.x;
  const float* sr = S + (size_t)row * NROWS;
  float s = 0.f;
  for (int b = threadIdx.x; b < NROWS; b += 256) s += __expf(sr[b]);
#pragma unroll
  for (int off = 32; off > 0; off >>= 1) s += __shfl_down(s, off, 64);
  __shared__ float wsum[4];
  if ((threadIdx.x & 63) == 0) wsum[threadIdx.x >> 6] = s;
  __syncthreads();
  if (threadIdx.x == 0) T[row] = wsum[0] + wsum[1] + wsum[2] + wsum[3];
}

__global__ __launch_bounds__(64) void k_dsum(const float* __restrict__ S,
                                             const float* __restrict__ T,
                                             float* __restrict__ Ds) {
  const int p = blockIdx.x;
  const int k = blockIdx.y;
  const int a = 12 * (p >> 2) + (p & 3);
  const int lane = threadIdx.x;
  const int row = (a + 4 * k) & (NROWS - 1);
  const int m = a >> 2;
  const int c = a & 3;
  const float4* sr4 = (const float4*)(S + (size_t)row * NROWS);
  float s = 0.f;
  {
    float4 v0 = sr4[(m + lane) & 511];
    float4 v1 = sr4[(m + 64 + lane) & 511];
    float e0 = c == 0 ? v0.x : c == 1 ? v0.y : c == 2 ? v0.z : v0.w;
    float e1 = c == 0 ? v1.x : c == 1 ? v1.y : c == 2 ? v1.z : v1.w;
    s += __expf(e0) + __expf(e1);
    if (lane < 32) {
      float4 v2 = sr4[(m + 128 + lane) & 511];
      float e2 = c == 0 ? v2.x : c == 1 ? v2.y : c == 2 ? v2.z : v2.w;
      s += __expf(e2);
    }
  }
#pragma unroll
  for (int off = 32; off > 0; off >>= 1) s += __shfl_down(s, off, 64);
  if (lane == 0) Ds[p * 6 + k] = T[row] - s;
}

__global__ __launch_bounds__(256) void k_final(const float* __restrict__ S,
                                               const float* __restrict__ Ds,
                                               float* __restrict__ out) {
  const int pa[7] = {0, 1, 0, 3, 4, 1, 2};
  const int pb[7] = {1, 2, 3, 4, 5, 4, 5};
  const int idx = blockIdx.x * 256 + threadIdx.x;
  float s = 0.f;
  if (idx < NACT * 7) {
    const int p = idx / 7;
    const int q = idx - p * 7;
    const int a0 = 12 * (p >> 2) + (p & 3);
    const int ra = (a0 + 4 * pa[q]) & (NROWS - 1);
    const int rb = (a0 + 4 * pb[q]) & (NROWS - 1);
    const float num = S[(size_t)ra * NROWS + rb];
    const float en = __expf(num);
    s = __logf(en + Ds[p * 6 + pa[q]]) + __logf(en + Ds[p * 6 + pb[q]]) - 2.f * num;
  }
#pragma unroll
  for (int off = 32; off > 0; off >>= 1) s += __shfl_down(s, off, 64);
  if ((threadIdx.x & 63) == 0) atomicAdd(out, s * (1.0f / (6.0f * 512.0f)));
}

extern "C" void kernel_launch(void* const* d_in, const int* in_sizes, int n_in,
                              void* d_out, int out_size, void* d_ws, size_t ws_size,
                              hipStream_t stream) {
  const float* X = (const float*)d_in[0];
  char* ws = (char*)d_ws;
  float* out = (float*)d_out;

  const size_t pOff = (size_t)32 * 1024 * 1024;
  const size_t pBytes = (size_t)NTILE * KSPLIT * 16384 * 2;     // 17.8 MB bf16 partials
  const size_t needA = pOff + pBytes + 8192 + NACT * 6 * 4 + 256;

  hipMemsetAsync(out, 0, sizeof(float), stream);

  if (ws_size >= needA) {
    unsigned char* Yq = (unsigned char*)ws;                       // 8 MB fp8
    unsigned short* S16 = (unsigned short*)(ws + (size_t)16 * 1024 * 1024); // 8 MB fp16
    unsigned short* P = (unsigned short*)(ws + pOff);
    float* T  = (float*)(ws + pOff + pBytes);
    float* Ds = (float*)(ws + pOff + pBytes + 8192);
    hipMemsetAsync(T, 0, NROWS * sizeof(float), stream);
    hipLaunchKernelGGL(k_normconv_fp8, dim3(NROWS), dim3(256), 0, stream, X, Yq);
    hipLaunchKernelGGL(k_gemm_sym, dim3(NTILE * KSPLIT), dim3(256), 0, stream, Yq, P);
    hipLaunchKernelGGL(k_combine, dim3(NTILE, 4), dim3(256), 0, stream, P, S16, T);
    hipLaunchKernelGGL(k_dsum_h, dim3(NACT, 6), dim3(64), 0, stream, S16, T, Ds);
    hipLaunchKernelGGL(k_final_h, dim3((NACT * 7 + 255) / 256), dim3(256), 0, stream, S16, Ds, out);
  } else {
    unsigned short* Y = (unsigned short*)ws;                      // 16 MB bf16
    float* S = (float*)(ws + (size_t)16 * 1024 * 1024);           // 16 MB fp32
    float* T  = (float*)(ws + pOff);
    float* Ds = (float*)(ws + pOff + 8192);
    hipLaunchKernelGGL(k_normconv, dim3(NROWS), dim3(256), 0, stream, X, Y);
    hipLaunchKernelGGL(k_gemm, dim3(16, 16), dim3(256), 0, stream, Y, S);
    hipLaunchKernelGGL(k_rowsum, dim3(NROWS), dim3(256), 0, stream, S, T);
    hipLaunchKernelGGL(k_dsum, dim3(NACT, 6), dim3(64), 0, stream, S, T, Ds);
    hipLaunchKernelGGL(k_final, dim3((NACT * 7 + 255) / 256), dim3(256), 0, stream, S, Ds, out);
  }
}